// Round 6
// baseline (3517.267 us; speedup 1.0000x reference)
//
#include <hip/hip_runtime.h>
#include <hip/hip_bf16.h>
#include <math.h>

#define NROWS 8192
#define DFEAT 2048
#define KSEL  64
#define CHK   2048   // symmetric pair chunk

typedef unsigned long long u64;
typedef __attribute__((ext_vector_type(8))) short bf16x8;
typedef __attribute__((ext_vector_type(4))) float f32x4;

__device__ __forceinline__ u64 umax64(u64 a, u64 b) { return a > b ? a : b; }

__device__ __forceinline__ void split2(float v, ushort& h, ushort& l) {
  __hip_bfloat16 bh = __float2bfloat16(v);
  float r = v - __bfloat162float(bh);
  __hip_bfloat16 bl = __float2bfloat16(r);
  h = *(ushort*)&bh; l = *(ushort*)&bl;
}

__device__ __forceinline__ u64 mkkey_vi(float v, int i) {
  unsigned u = __float_as_uint(v);
  u = ((int)u < 0) ? ~u : (u | 0x80000000u);
  return ((u64)u << 32) | (u64)(0xFFFFFFFFu - (unsigned)i);
}

// ---------------- K0: 3-way bf16 split of F (exact to 2^-27) ----------------
__global__ __launch_bounds__(256) void k_split(const float* __restrict__ F, ushort* __restrict__ H,
                                               ushort* __restrict__ M, ushort* __restrict__ L) {
  const size_t i0 = ((size_t)blockIdx.x * 256 + threadIdx.x) * 4;
  float4 x = *(const float4*)(F + i0);
  float xs[4] = {x.x, x.y, x.z, x.w};
  ushort h[4], m[4], l[4];
#pragma unroll
  for (int c = 0; c < 4; ++c) {
    float v = xs[c];
    __hip_bfloat16 bh = __float2bfloat16(v);
    float r1 = v - __bfloat162float(bh);
    __hip_bfloat16 bm = __float2bfloat16(r1);
    float r2 = r1 - __bfloat162float(bm);
    __hip_bfloat16 bl = __float2bfloat16(r2);
    h[c] = *(ushort*)&bh; m[c] = *(ushort*)&bm; l[c] = *(ushort*)&bl;
  }
  ushort4 vh = {h[0], h[1], h[2], h[3]};
  ushort4 vm = {m[0], m[1], m[2], m[3]};
  ushort4 vl = {l[0], l[1], l[2], l[3]};
  *(ushort4*)(H + i0) = vh;
  *(ushort4*)(M + i0) = vm;
  *(ushort4*)(L + i0) = vl;
}

// ---------------- K1p: symmetric pair tile GEMM (bf16x6), 2 pairs per launch ----------------
// Computes TILE[a][b] = sim(ci*CHK + a, cj*CHK + b) for a,b in [0,2048); optionally TILT = TILE^T.
__global__ __launch_bounds__(256) void k_simgemm_pair(
    const ushort* __restrict__ FH, const ushort* __restrict__ FM, const ushort* __restrict__ FL,
    float* __restrict__ T0, float* __restrict__ T0T, int i0, int j0,
    float* __restrict__ T1, float* __restrict__ T1T, int i1, int j1) {
  __shared__ ushort lds[6 * 4096];
  const int z = blockIdx.z;
  float* TILE = z ? T1 : T0;
  float* TILT = z ? T1T : T0T;
  const int ci = z ? i1 : i0;
  const int cj = z ? j1 : j0;
  const int bj = blockIdx.x;
  const int bm = blockIdx.y;
  const int t = threadIdx.x;
  const int w = t >> 6, l = t & 63;
  const int arow0 = ci * CHK + bm * 128;
  const int brow0 = cj * CHK + bj * 128;
  const int segr = l >> 2;
  const int segq = l & 3;
  const int fl15 = l & 15, fq = l >> 4;
  const int wr = w >> 1, wc = w & 1;
  const int mb = wr * 64, nb = wc * 64;

  f32x4 acc[4][4];
#pragma unroll
  for (int i = 0; i < 4; ++i)
#pragma unroll
    for (int j = 0; j < 4; ++j) acc[i][j] = (f32x4){0.f, 0.f, 0.f, 0.f};

  for (int k0 = 0; k0 < DFEAT; k0 += 32) {
    __syncthreads();
#pragma unroll
    for (int c = 0; c < 12; ++c) {
      const int cc = w * 12 + c;
      const int tt = cc >> 3;
      const int p = cc & 7;
      const int rowbase = (tt < 3) ? arow0 : brow0;
      const int sp = (tt < 3) ? tt : (tt - 3);
      const ushort* sel = (sp == 0) ? FH : ((sp == 1) ? FM : FL);
      const ushort* g = sel + (size_t)(rowbase + p * 16 + segr) * DFEAT + (k0 + segq * 8);
      __builtin_amdgcn_global_load_lds((const __attribute__((address_space(1))) unsigned int*)g,
                                       (__attribute__((address_space(3))) unsigned int*)&lds[tt * 4096 + p * 512],
                                       16, 0, 0);
    }
    __syncthreads();

    bf16x8 af[3][4];
    bf16x8 bg[3][4];
    const int kcol = fq * 8;
#pragma unroll
    for (int i = 0; i < 3; ++i)
#pragma unroll
      for (int fm = 0; fm < 4; ++fm)
        af[i][fm] = *(const bf16x8*)&lds[i * 4096 + (mb + fm * 16 + fl15) * 32 + kcol];
#pragma unroll
    for (int j = 0; j < 3; ++j)
#pragma unroll
      for (int fn = 0; fn < 4; ++fn)
        bg[j][fn] = *(const bf16x8*)&lds[(3 + j) * 4096 + (nb + fn * 16 + fl15) * 32 + kcol];

#pragma unroll
    for (int fm = 0; fm < 4; ++fm)
#pragma unroll
      for (int fn = 0; fn < 4; ++fn) {
        f32x4 a = acc[fm][fn];
        a = __builtin_amdgcn_mfma_f32_16x16x32_bf16(af[0][fm], bg[0][fn], a, 0, 0, 0);
        a = __builtin_amdgcn_mfma_f32_16x16x32_bf16(af[1][fm], bg[0][fn], a, 0, 0, 0);
        a = __builtin_amdgcn_mfma_f32_16x16x32_bf16(af[0][fm], bg[1][fn], a, 0, 0, 0);
        a = __builtin_amdgcn_mfma_f32_16x16x32_bf16(af[2][fm], bg[0][fn], a, 0, 0, 0);
        a = __builtin_amdgcn_mfma_f32_16x16x32_bf16(af[0][fm], bg[2][fn], a, 0, 0, 0);
        a = __builtin_amdgcn_mfma_f32_16x16x32_bf16(af[1][fm], bg[1][fn], a, 0, 0, 0);
        acc[fm][fn] = a;
      }
  }

#pragma unroll
  for (int fm = 0; fm < 4; ++fm) {
    const int lm = bm * 128 + mb + fm * 16 + fq * 4;  // local row (multiple of 4)
#pragma unroll
    for (int fn = 0; fn < 4; ++fn) {
      const int col = bj * 128 + nb + fn * 16 + fl15;  // local col
#pragma unroll
      for (int r = 0; r < 4; ++r)
        TILE[(size_t)(lm + r) * CHK + col] = acc[fm][fn][r];
      if (TILT) {
        float4 v = make_float4(acc[fm][fn][0], acc[fm][fn][1], acc[fm][fn][2], acc[fm][fn][3]);
        *(float4*)(TILT + (size_t)col * CHK + lm) = v;  // rows contiguous -> float4
      }
    }
  }
}

// ---------------- K1: chunked row-panel sim (fallback, proven) ----------------
__global__ __launch_bounds__(256) void k_simgemm_mfma(
    const ushort* __restrict__ FH, const ushort* __restrict__ FM, const ushort* __restrict__ FL,
    float* __restrict__ C, int row0) {
  __shared__ ushort lds[6 * 4096];
  const int bj = blockIdx.x;
  const int bm = blockIdx.y;
  const int t = threadIdx.x;
  const int w = t >> 6, l = t & 63;
  const int arow0 = row0 + bm * 128;
  const int brow0 = bj * 128;
  const int segr = l >> 2;
  const int segq = l & 3;
  const int fl15 = l & 15, fq = l >> 4;
  const int wr = w >> 1, wc = w & 1;
  const int mb = wr * 64, nb = wc * 64;

  f32x4 acc[4][4];
#pragma unroll
  for (int i = 0; i < 4; ++i)
#pragma unroll
    for (int j = 0; j < 4; ++j) acc[i][j] = (f32x4){0.f, 0.f, 0.f, 0.f};

  for (int k0 = 0; k0 < DFEAT; k0 += 32) {
    __syncthreads();
#pragma unroll
    for (int c = 0; c < 12; ++c) {
      const int cc = w * 12 + c;
      const int tt = cc >> 3;
      const int p = cc & 7;
      const int rowbase = (tt < 3) ? arow0 : brow0;
      const int sp = (tt < 3) ? tt : (tt - 3);
      const ushort* sel = (sp == 0) ? FH : ((sp == 1) ? FM : FL);
      const ushort* g = sel + (size_t)(rowbase + p * 16 + segr) * DFEAT + (k0 + segq * 8);
      __builtin_amdgcn_global_load_lds((const __attribute__((address_space(1))) unsigned int*)g,
                                       (__attribute__((address_space(3))) unsigned int*)&lds[tt * 4096 + p * 512],
                                       16, 0, 0);
    }
    __syncthreads();

    bf16x8 af[3][4];
    bf16x8 bg[3][4];
    const int kcol = fq * 8;
#pragma unroll
    for (int i = 0; i < 3; ++i)
#pragma unroll
      for (int fm = 0; fm < 4; ++fm)
        af[i][fm] = *(const bf16x8*)&lds[i * 4096 + (mb + fm * 16 + fl15) * 32 + kcol];
#pragma unroll
    for (int j = 0; j < 3; ++j)
#pragma unroll
      for (int fn = 0; fn < 4; ++fn)
        bg[j][fn] = *(const bf16x8*)&lds[(3 + j) * 4096 + (nb + fn * 16 + fl15) * 32 + kcol];

#pragma unroll
    for (int fm = 0; fm < 4; ++fm)
#pragma unroll
      for (int fn = 0; fn < 4; ++fn) {
        f32x4 a = acc[fm][fn];
        a = __builtin_amdgcn_mfma_f32_16x16x32_bf16(af[0][fm], bg[0][fn], a, 0, 0, 0);
        a = __builtin_amdgcn_mfma_f32_16x16x32_bf16(af[1][fm], bg[0][fn], a, 0, 0, 0);
        a = __builtin_amdgcn_mfma_f32_16x16x32_bf16(af[0][fm], bg[1][fn], a, 0, 0, 0);
        a = __builtin_amdgcn_mfma_f32_16x16x32_bf16(af[2][fm], bg[0][fn], a, 0, 0, 0);
        a = __builtin_amdgcn_mfma_f32_16x16x32_bf16(af[0][fm], bg[2][fn], a, 0, 0, 0);
        a = __builtin_amdgcn_mfma_f32_16x16x32_bf16(af[1][fm], bg[1][fn], a, 0, 0, 0);
        acc[fm][fn] = a;
      }
  }

#pragma unroll
  for (int fm = 0; fm < 4; ++fm) {
    const int lm = bm * 128 + mb + fm * 16 + fq * 4;
#pragma unroll
    for (int fn = 0; fn < 4; ++fn) {
      const int col = bj * 128 + nb + fn * 16 + fl15;
#pragma unroll
      for (int r = 0; r < 4; ++r)
        C[(size_t)(lm + r) * NROWS + col] = acc[fm][fn][r];
    }
  }
}

// ---------------- K1b: generic bf16x3 MFMA GEMM: C = A . B^T ----------------
__global__ __launch_bounds__(256) void k_gemm3(const ushort* __restrict__ AH, const ushort* __restrict__ AL,
                                               const ushort* __restrict__ BH, const ushort* __restrict__ BL,
                                               float* __restrict__ C, int K, int N) {
  __shared__ ushort lds[4 * 4096];
  const int bj = blockIdx.x, bm = blockIdx.y;
  const int t = threadIdx.x;
  const int w = t >> 6, l = t & 63;
  const int segr = l >> 2, segq = l & 3;
  const int fl15 = l & 15, fq = l >> 4;
  const int wr = w >> 1, wc = w & 1;
  const int mb = wr * 64, nb = wc * 64;

  f32x4 acc[4][4];
#pragma unroll
  for (int i = 0; i < 4; ++i)
#pragma unroll
    for (int j = 0; j < 4; ++j) acc[i][j] = (f32x4){0.f, 0.f, 0.f, 0.f};

  for (int k0 = 0; k0 < K; k0 += 32) {
    __syncthreads();
#pragma unroll
    for (int c = 0; c < 8; ++c) {
      const int s = w * 8 + c;
      const int tt = s >> 3;          // 0=AH 1=AL 2=BH 3=BL
      const int p = s & 7;
      const int rowbase = (tt < 2) ? (bm * 128) : (bj * 128);
      const ushort* sel = (tt == 0) ? AH : ((tt == 1) ? AL : ((tt == 2) ? BH : BL));
      const ushort* g = sel + (size_t)(rowbase + p * 16 + segr) * K + (k0 + segq * 8);
      __builtin_amdgcn_global_load_lds((const __attribute__((address_space(1))) unsigned int*)g,
                                       (__attribute__((address_space(3))) unsigned int*)&lds[s * 512],
                                       16, 0, 0);
    }
    __syncthreads();

    bf16x8 af[2][4];
    bf16x8 bg[2][4];
    const int kcol = fq * 8;
#pragma unroll
    for (int i = 0; i < 2; ++i)
#pragma unroll
      for (int fm = 0; fm < 4; ++fm)
        af[i][fm] = *(const bf16x8*)&lds[i * 4096 + (mb + fm * 16 + fl15) * 32 + kcol];
#pragma unroll
    for (int j = 0; j < 2; ++j)
#pragma unroll
      for (int fn = 0; fn < 4; ++fn)
        bg[j][fn] = *(const bf16x8*)&lds[(2 + j) * 4096 + (nb + fn * 16 + fl15) * 32 + kcol];

#pragma unroll
    for (int fm = 0; fm < 4; ++fm)
#pragma unroll
      for (int fn = 0; fn < 4; ++fn) {
        f32x4 a = acc[fm][fn];
        a = __builtin_amdgcn_mfma_f32_16x16x32_bf16(af[0][fm], bg[0][fn], a, 0, 0, 0);
        a = __builtin_amdgcn_mfma_f32_16x16x32_bf16(af[0][fm], bg[1][fn], a, 0, 0, 0);
        a = __builtin_amdgcn_mfma_f32_16x16x32_bf16(af[1][fm], bg[0][fn], a, 0, 0, 0);
        acc[fm][fn] = a;
      }
  }

#pragma unroll
  for (int fm = 0; fm < 4; ++fm) {
    const int row = bm * 128 + mb + fm * 16 + fq * 4;
#pragma unroll
    for (int fn = 0; fn < 4; ++fn) {
      const int col = bj * 128 + nb + fn * 16 + fl15;
#pragma unroll
      for (int r = 0; r < 4; ++r)
        C[(size_t)(row + r) * N + col] = acc[fm][fn][r];
    }
  }
}

// ---------------- K2i: init running top-k ----------------
__global__ __launch_bounds__(256) void k_init_topk(float* __restrict__ topv, int* __restrict__ topi) {
  const int i = blockIdx.x * 256 + threadIdx.x;
  topv[i] = -INFINITY;
  topi[i] = 0;
}

// ---------------- K2u: merge-update running top-64 with one 2048-col tile slice ----------------
__global__ __launch_bounds__(256) void k_topk_update(const float* __restrict__ T, int rowbase, int colbase,
                                                     float* __restrict__ topv, int* __restrict__ topi) {
  __shared__ float vals[CHK + KSEL];
  __shared__ int oidx[KSEL];
  __shared__ u64 wmax[4];
  __shared__ float outv[KSEL];
  __shared__ int outi[KSEL];
  const int t = threadIdx.x;
  const int row = rowbase + blockIdx.x;
  const float* src = T + (size_t)blockIdx.x * CHK;
  for (int i = t; i < CHK; i += 256) vals[i] = src[i];
  if (t < KSEL) {
    vals[CHK + t] = topv[(size_t)row * KSEL + t];
    oidx[t] = topi[(size_t)row * KSEL + t];
  }
  __syncthreads();

  auto gidx = [&](int slot) -> int {
    return (slot < CHK) ? (colbase + slot) : oidx[slot - CHK];
  };

  u64 lk = 0;
#pragma unroll
  for (int m = 0; m < 9; ++m) {
    const int s = t + 256 * m;
    if (s < CHK + KSEL) lk = umax64(lk, mkkey_vi(vals[s], gidx(s)));
  }

  const int lane = t & 63, wv = t >> 6;
  for (int it = 0; it < KSEL; ++it) {
    u64 wk = lk;
#pragma unroll
    for (int s = 32; s > 0; s >>= 1) {
      u64 o = __shfl_xor(wk, s);
      wk = umax64(wk, o);
    }
    if (lane == 0) wmax[wv] = wk;
    __syncthreads();
    const u64 g = umax64(umax64(wmax[0], wmax[1]), umax64(wmax[2], wmax[3]));
    const unsigned ui = (unsigned)(g >> 32);
    const float v = __uint_as_float((ui & 0x80000000u) ? (ui ^ 0x80000000u) : ~ui);
    const int idx = (int)(0xFFFFFFFFu - (unsigned)(g & 0xFFFFFFFFull));
    if (t == 0) { outv[it] = v; outi[it] = idx; }
    // invalidate + owner recompute
    bool own = false;
#pragma unroll
    for (int m = 0; m < 9; ++m) {
      const int s = t + 256 * m;
      if (s < CHK + KSEL && gidx(s) == idx) { vals[s] = -INFINITY; own = true; }
    }
    if (own) {
      u64 nl = 0;
#pragma unroll
      for (int m = 0; m < 9; ++m) {
        const int s = t + 256 * m;
        if (s < CHK + KSEL) nl = umax64(nl, mkkey_vi(vals[s], gidx(s)));
      }
      lk = nl;
    }
    __syncthreads();
  }
  if (t < KSEL) {
    topv[(size_t)row * KSEL + t] = outv[t];
    topi[(size_t)row * KSEL + t] = outi[t];
  }
}

// ---------------- K2e: exps from final top-10 ----------------
__global__ __launch_bounds__(256) void k_exps(const float* __restrict__ topv, float* __restrict__ exps) {
  const int r = blockIdx.x * 256 + threadIdx.x;
  float s = 0.f;
#pragma unroll
  for (int q = 0; q < 10; ++q) s += topv[(size_t)r * KSEL + q];
  exps[r] = expf(s / 40.0f);
}

// ---------------- K2: full-row top-64 (fallback path) ----------------
__global__ __launch_bounds__(256) void k_topk(const float* __restrict__ simc,
                                              float* __restrict__ topv, int* __restrict__ topi,
                                              float* __restrict__ exps, int row0) {
  __shared__ float vals[NROWS];
  __shared__ u64 wmax[4];
  __shared__ float outv[KSEL];
  __shared__ int outi[KSEL];
  const int row = row0 + blockIdx.x;
  const int t = threadIdx.x;
  const float* src = simc + (size_t)blockIdx.x * NROWS;
  for (int i = t; i < NROWS; i += 256) vals[i] = src[i];
  __syncthreads();

  u64 lk = 0;
#pragma unroll
  for (int m = 0; m < 32; ++m) {
    int i = t + 256 * m;
    lk = umax64(lk, mkkey_vi(vals[i], i));
  }

  const int lane = t & 63, wv = t >> 6;
  for (int it = 0; it < KSEL; ++it) {
    u64 wk = lk;
#pragma unroll
    for (int s = 32; s > 0; s >>= 1) {
      u64 o = __shfl_xor(wk, s);
      wk = umax64(wk, o);
    }
    if (lane == 0) wmax[wv] = wk;
    __syncthreads();
    u64 g = umax64(umax64(wmax[0], wmax[1]), umax64(wmax[2], wmax[3]));
    const unsigned ui = (unsigned)(g >> 32);
    const float v = __uint_as_float((ui & 0x80000000u) ? (ui ^ 0x80000000u) : ~ui);
    const int idx = (int)(0xFFFFFFFFu - (unsigned)(g & 0xFFFFFFFFull));
    if (t == 0) { outv[it] = v; outi[it] = idx; }
    if (t == (idx & 255)) {
      vals[idx] = -INFINITY;
      u64 nl = 0;
#pragma unroll
      for (int m = 0; m < 32; ++m) {
        int i = t + 256 * m;
        nl = umax64(nl, mkkey_vi(vals[i], i));
      }
      lk = nl;
    }
    __syncthreads();
  }
  if (t < KSEL) {
    topv[(size_t)row * KSEL + t] = outv[t];
    topi[(size_t)row * KSEL + t] = outi[t];
  }
  if (t == 0) {
    float s = 0.f;
#pragma unroll
    for (int q = 0; q < 10; ++q) s += outv[q];
    exps[row] = expf(s / 40.0f);
  }
}

// ---------------- K3: adjacency build + row softmax ----------------
__global__ __launch_bounds__(256) void k_adj(const int* __restrict__ indexes,
                                             const float* __restrict__ topv, const int* __restrict__ topi,
                                             const float* __restrict__ exps, float* __restrict__ adj) {
  __shared__ int nbr[64];
  __shared__ int neigh[64][10];
  __shared__ float tv[64][10];
  __shared__ float adjL[64][64];
  const int b = blockIdx.x;
  const int t = threadIdx.x;
  const int idx = indexes[b];
  if (t < 64) nbr[t] = topi[(size_t)idx * KSEL + t];
  __syncthreads();
  for (int p = t; p < 640; p += 256) {
    const int r = p / 10, q = p - r * 10;
    const int m = nbr[r];
    const int c = topi[(size_t)m * KSEL + q];
    neigh[r][q] = c;
    tv[r][q] = topv[(size_t)m * KSEL + q] * exps[c];
  }
  __syncthreads();
  for (int p = t; p < 4096; p += 256) {
    const int i = p >> 6, j = p & 63;
    float s = 0.f;
#pragma unroll
    for (int q = 0; q < 10; ++q) {
      const int c = neigh[i][q];
      float add = 0.f;
      for (int s2 = 0; s2 < 10; ++s2) {
        if (neigh[j][s2] == c) { add = (tv[j][s2] > 0.f) ? tv[i][q] : 0.f; break; }
      }
      s += add;
    }
    adjL[i][j] = s;
  }
  __syncthreads();
  const int wv = t >> 6, lane = t & 63;
  for (int i = wv * 16; i < wv * 16 + 16; ++i) {
    float v = adjL[i][lane];
    float mx = v;
#pragma unroll
    for (int s = 32; s > 0; s >>= 1) mx = fmaxf(mx, __shfl_xor(mx, s));
    float e = expf(v - mx);
    float sum = e;
#pragma unroll
    for (int s = 32; s > 0; s >>= 1) sum += __shfl_xor(sum, s);
    adj[((size_t)b * 64 + i) * 64 + lane] = e / sum;
  }
}

// ---------------- K4: xs splits ----------------
__global__ __launch_bounds__(256) void k_xs_split(const int* __restrict__ indexes, const int* __restrict__ topi,
                                                  const float* __restrict__ F,
                                                  ushort* __restrict__ XH, ushort* __restrict__ XL) {
  const int b = blockIdx.y, r = blockIdx.x;
  const int t = threadIdx.x;
  const int idx = indexes[b];
  const int m  = topi[(size_t)idx * KSEL + r];
  const int m0 = topi[(size_t)idx * KSEL + 0];
  const float4* pa = (const float4*)(F + (size_t)m * DFEAT);
  const float4* pb = (const float4*)(F + (size_t)m0 * DFEAT);
  const size_t rowoff = ((size_t)b * 64 + r) * DFEAT;
#pragma unroll
  for (int it = 0; it < 2; ++it) {
    const int i = t + it * 256;
    float4 a = pa[i], c = pb[i];
    float d[4] = {a.x - c.x, a.y - c.y, a.z - c.z, a.w - c.w};
    ushort h[4], l[4];
#pragma unroll
    for (int q = 0; q < 4; ++q) split2(d[q], h[q], l[q]);
    ushort4 vh = {h[0], h[1], h[2], h[3]};
    ushort4 vl = {l[0], l[1], l[2], l[3]};
    *(ushort4*)(XH + rowoff + i * 4) = vh;
    *(ushort4*)(XL + rowoff + i * 4) = vl;
  }
}

// ---------------- K5: weight pre-split, transposed + combined ----------------
__global__ __launch_bounds__(256) void k_wsplitT(const float* __restrict__ W,
                                                 ushort* __restrict__ WTH, ushort* __restrict__ WTL,
                                                 int K, int F) {
  __shared__ float tile[32][33];
  const int k0 = blockIdx.x * 32;
  const int n0 = blockIdx.y * 32;
  const int t = threadIdx.x;
  {
    const int r = t >> 3, cq = t & 7;
    const int srcRow = (n0 < F) ? (k0 + r) : (K + k0 + r);
    const int srcCol = (n0 < F) ? n0 : (n0 - F);
    float4 v = *(const float4*)(W + (size_t)srcRow * F + srcCol + cq * 4);
    tile[r][cq * 4 + 0] = v.x; tile[r][cq * 4 + 1] = v.y;
    tile[r][cq * 4 + 2] = v.z; tile[r][cq * 4 + 3] = v.w;
  }
  __syncthreads();
  {
    const int nl = t >> 3, kq = t & 7;
    ushort h[4], l[4];
#pragma unroll
    for (int i = 0; i < 4; ++i) split2(tile[kq * 4 + i][nl], h[i], l[i]);
    ushort4 vh = {h[0], h[1], h[2], h[3]};
    ushort4 vl = {l[0], l[1], l[2], l[3]};
    *(ushort4*)(WTH + (size_t)(n0 + nl) * K + k0 + kq * 4) = vh;
    *(ushort4*)(WTL + (size_t)(n0 + nl) * K + k0 + kq * 4) = vl;
  }
}

// ---------------- K6: layer epilogue: h = relu(P + adj@Q + bias); out splits ----------------
__global__ __launch_bounds__(256) void k_postlayer(const float* __restrict__ C, const float* __restrict__ adj,
                                                   const float* __restrict__ bias,
                                                   ushort* __restrict__ HH, ushort* __restrict__ HL, int F) {
  __shared__ float adjL[64 * 65];
  __shared__ float QL[64 * 66];
  const int f0 = blockIdx.x * 64;
  const int b = blockIdx.y;
  const int t = threadIdx.x;
  const int fc = t & 63, rg = t >> 6;
  const int twoF = 2 * F;
  for (int i = t; i < 4096; i += 256) {
    const int r = i >> 6, j = i & 63;
    adjL[r * 65 + j] = adj[(size_t)b * 4096 + i];
    QL[r * 66 + j] = C[(size_t)(b * 64 + r) * twoF + F + f0 + j];
  }
  __syncthreads();
  const float bv = bias[f0 + fc];
  for (int rr = 0; rr < 16; ++rr) {
    const int r = rg * 16 + rr;
    float s = 0.f;
#pragma unroll 8
    for (int j0 = 0; j0 < 64; ++j0) {
      const int j = (j0 + fc) & 63;
      s += adjL[r * 65 + j] * QL[j * 66 + fc];
    }
    const int row = b * 64 + r;
    float h = C[(size_t)row * twoF + f0 + fc] + s + bv;
    h = fmaxf(h, 0.f);
    ushort hh, hl;
    split2(h, hh, hl);
    HH[(size_t)row * F + f0 + fc] = hh;
    HL[(size_t)row * F + f0 + fc] = hl;
  }
}

// ---------------- K7: classifier epilogue: HC = prelu(C + bc1) ----------------
__global__ __launch_bounds__(256) void k_postcls(const float* __restrict__ C, const float* __restrict__ bias,
                                                 const float* __restrict__ pre, float* __restrict__ HC) {
  const size_t i0 = ((size_t)blockIdx.x * 256 + threadIdx.x) * 4;
  const int col = (int)(i0 & 255);
  float4 c = *(const float4*)(C + i0);
  float o[4] = {c.x, c.y, c.z, c.w};
#pragma unroll
  for (int i = 0; i < 4; ++i) {
    float h = o[i] + bias[col + i];
    o[i] = (h > 0.f) ? h : pre[col + i] * h;
  }
  *(float4*)(HC + i0) = make_float4(o[0], o[1], o[2], o[3]);
}

// ---------------- K8: pred = HC @ Wc2 + bc2 ----------------
__global__ __launch_bounds__(256) void k_final(const float* __restrict__ Hc, const float* __restrict__ Wc2,
                                               const float* __restrict__ bc2, float* __restrict__ outp) {
  __shared__ float w[512];
  __shared__ float red[512];
  const int t = threadIdx.x;
  for (int i = t; i < 512; i += 256) w[i] = Wc2[i];
  __syncthreads();
  const int m = blockIdx.x * 64 + (t >> 2);
  const int p = t & 3;
  const float* h = Hc + (size_t)m * 256;
  float s0 = 0.f, s1 = 0.f;
  for (int k = p * 64; k < p * 64 + 64; ++k) {
    float hv = h[k];
    s0 += hv * w[k * 2];
    s1 += hv * w[k * 2 + 1];
  }
  red[t * 2] = s0; red[t * 2 + 1] = s1;
  __syncthreads();
  if (p == 0) {
    for (int q = 1; q < 4; ++q) { s0 += red[(t + q) * 2]; s1 += red[(t + q) * 2 + 1]; }
    outp[m * 2 + 0] = s0 + bc2[0];
    outp[m * 2 + 1] = s1 + bc2[1];
  }
}

extern "C" void kernel_launch(void* const* d_in, const int* in_sizes, int n_in,
                              void* d_out, int out_size, void* d_ws, size_t ws_size,
                              hipStream_t stream) {
  const int*   indexes = (const int*)d_in[0];
  const float* F   = (const float*)d_in[1];
  const float* W1  = (const float*)d_in[4];
  const float* b1  = (const float*)d_in[5];
  const float* W2  = (const float*)d_in[6];
  const float* b2  = (const float*)d_in[7];
  const float* W3  = (const float*)d_in[8];
  const float* b3  = (const float*)d_in[9];
  const float* W4  = (const float*)d_in[10];
  const float* b4  = (const float*)d_in[11];
  const float* Wc1 = (const float*)d_in[12];
  const float* bc1 = (const float*)d_in[13];
  const float* pre = (const float*)d_in[14];
  const float* Wc2 = (const float*)d_in[15];
  const float* bc2 = (const float*)d_in[16];
  float* out = (float*)d_out;

  // ---- fixed workspace ----
  size_t off = 0;
  auto take = [&](size_t bytes) -> char* {
    char* q = (char*)d_ws + off;
    off += (bytes + 255) & ~(size_t)255;
    return q;
  };
  float* TOPV = (float*)take((size_t)NROWS * KSEL * 4);
  int*   TOPI = (int*)  take((size_t)NROWS * KSEL * 4);
  float* EXPS = (float*)take((size_t)NROWS * 4);
  float* ADJ  = (float*)take((size_t)64 * 64 * 64 * 4);
  char*  big  = (char*)d_ws + off;
  const size_t big_bytes = (ws_size > off) ? (ws_size - off) : 0;

  const size_t Mi = 1024 * 1024;
  const size_t Ki = 1024;
  const size_t splitBytes = (size_t)NROWS * DFEAT * 2;  // 32 Mi per split of F

  // ---- phase A: sim + top-k ----
  if (big_bytes >= 160 * Mi) {
    // symmetric pair-tile path (10 of 16 tiles computed)
    ushort* FH = (ushort*)big;
    ushort* FM = (ushort*)(big + splitBytes);
    ushort* FL = (ushort*)(big + 2 * splitBytes);
    float* TILE0  = (float*)(big + 96 * Mi);
    float* TILE0T = (float*)(big + 112 * Mi);
    float* TILE1  = (float*)(big + 128 * Mi);
    float* TILE1T = (float*)(big + 144 * Mi);
    k_split<<<NROWS * DFEAT / 1024, 256, 0, stream>>>(F, FH, FM, FL);
    k_init_topk<<<NROWS * KSEL / 256, 256, 0, stream>>>(TOPV, TOPI);
    const int pairs[10][2] = {{0,0},{0,1},{0,2},{0,3},{1,1},{1,2},{1,3},{2,2},{2,3},{3,3}};
    for (int b = 0; b < 5; ++b) {
      const int ia = pairs[2*b][0],   ja = pairs[2*b][1];
      const int ib = pairs[2*b+1][0], jb = pairs[2*b+1][1];
      k_simgemm_pair<<<dim3(16, 16, 2), 256, 0, stream>>>(
          FH, FM, FL,
          TILE0, (ia != ja) ? TILE0T : nullptr, ia, ja,
          TILE1, (ib != jb) ? TILE1T : nullptr, ib, jb);
      k_topk_update<<<CHK, 256, 0, stream>>>(TILE0, ia * CHK, ja * CHK, TOPV, TOPI);
      if (ia != ja) k_topk_update<<<CHK, 256, 0, stream>>>(TILE0T, ja * CHK, ia * CHK, TOPV, TOPI);
      k_topk_update<<<CHK, 256, 0, stream>>>(TILE1, ib * CHK, jb * CHK, TOPV, TOPI);
      if (ib != jb) k_topk_update<<<CHK, 256, 0, stream>>>(TILE1T, jb * CHK, ib * CHK, TOPV, TOPI);
    }
    k_exps<<<NROWS / 256, 256, 0, stream>>>(TOPV, EXPS);
  } else {
    // fallback: chunked row-panel (R5 behavior)
    int fchunk = 0;
    for (int c = 2048; c >= 512; c >>= 1) {
      if (3 * splitBytes + (size_t)c * NROWS * 4 <= big_bytes) { fchunk = c; break; }
    }
    if (fchunk == 0) {
      hipMemsetAsync(d_out, 0, (size_t)out_size * 4, stream);
      return;
    }
    ushort* FH = (ushort*)big;
    ushort* FM = (ushort*)(big + splitBytes);
    ushort* FL = (ushort*)(big + 2 * splitBytes);
    float* SIMC = (float*)(big + 3 * splitBytes);
    k_split<<<NROWS * DFEAT / 1024, 256, 0, stream>>>(F, FH, FM, FL);
    for (int r0 = 0; r0 < NROWS; r0 += fchunk) {
      k_simgemm_mfma<<<dim3(64, fchunk / 128), 256, 0, stream>>>(FH, FM, FL, SIMC, r0);
      k_topk<<<fchunk, 256, 0, stream>>>(SIMC, TOPV, TOPI, EXPS, r0);
    }
  }
  k_adj<<<64, 256, 0, stream>>>(indexes, TOPV, TOPI, EXPS, ADJ);

  // ---- phase B layout (aliases phase-A region; lifetime-checked, same as R5) ----
  ushort* XH   = (ushort*)(big);                         //  0..16 Mi
  ushort* XL   = (ushort*)(big + 16 * Mi);               // 16..32 Mi
  ushort* WT1H = (ushort*)(big + 32 * Mi);               // 32..40 Mi
  ushort* WT1L = (ushort*)(big + 40 * Mi);               // 40..48 Mi
  ushort* WT2H = (ushort*)(big + 48 * Mi);               // 48..50 Mi
  ushort* WT2L = (ushort*)(big + 50 * Mi);               // 50..52 Mi
  ushort* WT3H = (ushort*)(big + 52 * Mi);               // 52..52.5 Mi
  ushort* WT3L = (ushort*)(big + 52 * Mi + 512 * Ki);    // 52.5..53 Mi
  ushort* WT4H = (ushort*)(big + 53 * Mi);               // 53..53.25 Mi
  ushort* WT4L = (ushort*)(big + 53 * Mi + 256 * Ki);    // 53.25..53.5 Mi
  ushort* WTcH = (ushort*)(big + 53 * Mi + 512 * Ki);    // 53.5..53.625 Mi
  ushort* WTcL = (ushort*)(big + 53 * Mi + 640 * Ki);    // 53.625..53.75 Mi
  float*  CBUF = (float*)(big + 54 * Mi);                // 54..86 Mi
  float*  HC   = (float*)(big + 86 * Mi);                // 86..90 Mi
  ushort* H1H  = (ushort*)(big + 32 * Mi);               // alias WT1 (dead after L1 gemm)
  ushort* H1L  = (ushort*)(big + 40 * Mi);
  ushort* H2H  = (ushort*)(big);                         //  0..4 Mi   (alias XS)
  ushort* H2L  = (ushort*)(big + 4 * Mi);                //  4..8 Mi
  ushort* H3H  = (ushort*)(big + 8 * Mi);                //  8..10 Mi
  ushort* H3L  = (ushort*)(big + 10 * Mi);               // 10..12 Mi
  ushort* H4H  = (ushort*)(big + 12 * Mi);               // 12..14 Mi
  ushort* H4L  = (ushort*)(big + 14 * Mi);               // 14..16 Mi

  k_wsplitT<<<dim3(2048 / 32, 2048 / 32), 256, 0, stream>>>(W1, WT1H, WT1L, 2048, 1024);
  k_wsplitT<<<dim3(1024 / 32, 1024 / 32), 256, 0, stream>>>(W2, WT2H, WT2L, 1024, 512);
  k_wsplitT<<<dim3(512 / 32, 512 / 32), 256, 0, stream>>>(W3, WT3H, WT3L, 512, 256);
  k_wsplitT<<<dim3(256 / 32, 512 / 32), 256, 0, stream>>>(W4, WT4H, WT4L, 256, 256);
  k_wsplitT<<<dim3(256 / 32, 256 / 32), 256, 0, stream>>>(Wc1, WTcH, WTcL, 256, 256);

  k_xs_split<<<dim3(64, 64), 256, 0, stream>>>(indexes, TOPI, F, XH, XL);

  k_gemm3<<<dim3(16, 32), 256, 0, stream>>>(XH, XL, WT1H, WT1L, CBUF, 2048, 2048);
  k_postlayer<<<dim3(16, 64), 256, 0, stream>>>(CBUF, ADJ, b1, H1H, H1L, 1024);
  k_gemm3<<<dim3(8, 32), 256, 0, stream>>>(H1H, H1L, WT2H, WT2L, CBUF, 1024, 1024);
  k_postlayer<<<dim3(8, 64), 256, 0, stream>>>(CBUF, ADJ, b2, H2H, H2L, 512);
  k_gemm3<<<dim3(4, 32), 256, 0, stream>>>(H2H, H2L, WT3H, WT3L, CBUF, 512, 512);
  k_postlayer<<<dim3(4, 64), 256, 0, stream>>>(CBUF, ADJ, b3, H3H, H3L, 256);
  k_gemm3<<<dim3(4, 32), 256, 0, stream>>>(H3H, H3L, WT4H, WT4L, CBUF, 256, 512);
  k_postlayer<<<dim3(4, 64), 256, 0, stream>>>(CBUF, ADJ, b4, H4H, H4L, 256);
  k_gemm3<<<dim3(2, 32), 256, 0, stream>>>(H4H, H4L, WTcH, WTcL, CBUF, 256, 256);
  k_postcls<<<4096 * 256 / 1024, 256, 0, stream>>>(CBUF, bc1, pre, HC);

  k_final<<<64, 256, 0, stream>>>(HC, Wc2, bc2, out);
}

// Round 7
// 2221.728 us; speedup vs baseline: 1.5831x; 1.5831x over previous
//
#include <hip/hip_runtime.h>
#include <hip/hip_bf16.h>
#include <math.h>

#define NROWS 8192
#define DFEAT 2048
#define KSEL  64
#define CHK   2048   // symmetric pair chunk

typedef unsigned long long u64;
typedef __attribute__((ext_vector_type(8))) short bf16x8;
typedef __attribute__((ext_vector_type(4))) float f32x4;

__device__ __forceinline__ u64 umax64(u64 a, u64 b) { return a > b ? a : b; }

__device__ __forceinline__ void split2(float v, ushort& h, ushort& l) {
  __hip_bfloat16 bh = __float2bfloat16(v);
  float r = v - __bfloat162float(bh);
  __hip_bfloat16 bl = __float2bfloat16(r);
  h = *(ushort*)&bh; l = *(ushort*)&bl;
}

__device__ __forceinline__ u64 mkkey_vi(float v, int i) {
  unsigned u = __float_as_uint(v);
  u = ((int)u < 0) ? ~u : (u | 0x80000000u);
  return ((u64)u << 32) | (u64)(0xFFFFFFFFu - (unsigned)i);
}

// ---------------- K0: 3-way bf16 split of F (exact to 2^-27) ----------------
__global__ __launch_bounds__(256) void k_split(const float* __restrict__ F, ushort* __restrict__ H,
                                               ushort* __restrict__ M, ushort* __restrict__ L) {
  const size_t i0 = ((size_t)blockIdx.x * 256 + threadIdx.x) * 4;
  float4 x = *(const float4*)(F + i0);
  float xs[4] = {x.x, x.y, x.z, x.w};
  ushort h[4], m[4], l[4];
#pragma unroll
  for (int c = 0; c < 4; ++c) {
    float v = xs[c];
    __hip_bfloat16 bh = __float2bfloat16(v);
    float r1 = v - __bfloat162float(bh);
    __hip_bfloat16 bm = __float2bfloat16(r1);
    float r2 = r1 - __bfloat162float(bm);
    __hip_bfloat16 bl = __float2bfloat16(r2);
    h[c] = *(ushort*)&bh; m[c] = *(ushort*)&bm; l[c] = *(ushort*)&bl;
  }
  ushort4 vh = {h[0], h[1], h[2], h[3]};
  ushort4 vm = {m[0], m[1], m[2], m[3]};
  ushort4 vl = {l[0], l[1], l[2], l[3]};
  *(ushort4*)(H + i0) = vh;
  *(ushort4*)(M + i0) = vm;
  *(ushort4*)(L + i0) = vl;
}

// ---------------- K1p: symmetric pair tile GEMM (bf16x6), 2 pairs per launch ----------------
__global__ __launch_bounds__(256) void k_simgemm_pair(
    const ushort* __restrict__ FH, const ushort* __restrict__ FM, const ushort* __restrict__ FL,
    float* __restrict__ T0, float* __restrict__ T0T, int i0, int j0,
    float* __restrict__ T1, float* __restrict__ T1T, int i1, int j1) {
  __shared__ ushort lds[6 * 4096];
  const int z = blockIdx.z;
  float* TILE = z ? T1 : T0;
  float* TILT = z ? T1T : T0T;
  const int ci = z ? i1 : i0;
  const int cj = z ? j1 : j0;
  const int bj = blockIdx.x;
  const int bm = blockIdx.y;
  const int t = threadIdx.x;
  const int w = t >> 6, l = t & 63;
  const int arow0 = ci * CHK + bm * 128;
  const int brow0 = cj * CHK + bj * 128;
  const int segr = l >> 2;
  const int segq = l & 3;
  const int fl15 = l & 15, fq = l >> 4;
  const int wr = w >> 1, wc = w & 1;
  const int mb = wr * 64, nb = wc * 64;

  f32x4 acc[4][4];
#pragma unroll
  for (int i = 0; i < 4; ++i)
#pragma unroll
    for (int j = 0; j < 4; ++j) acc[i][j] = (f32x4){0.f, 0.f, 0.f, 0.f};

  for (int k0 = 0; k0 < DFEAT; k0 += 32) {
    __syncthreads();
#pragma unroll
    for (int c = 0; c < 12; ++c) {
      const int cc = w * 12 + c;
      const int tt = cc >> 3;
      const int p = cc & 7;
      const int rowbase = (tt < 3) ? arow0 : brow0;
      const int sp = (tt < 3) ? tt : (tt - 3);
      const ushort* sel = (sp == 0) ? FH : ((sp == 1) ? FM : FL);
      const ushort* g = sel + (size_t)(rowbase + p * 16 + segr) * DFEAT + (k0 + segq * 8);
      __builtin_amdgcn_global_load_lds((const __attribute__((address_space(1))) unsigned int*)g,
                                       (__attribute__((address_space(3))) unsigned int*)&lds[tt * 4096 + p * 512],
                                       16, 0, 0);
    }
    __syncthreads();

    bf16x8 af[3][4];
    bf16x8 bg[3][4];
    const int kcol = fq * 8;
#pragma unroll
    for (int i = 0; i < 3; ++i)
#pragma unroll
      for (int fm = 0; fm < 4; ++fm)
        af[i][fm] = *(const bf16x8*)&lds[i * 4096 + (mb + fm * 16 + fl15) * 32 + kcol];
#pragma unroll
    for (int j = 0; j < 3; ++j)
#pragma unroll
      for (int fn = 0; fn < 4; ++fn)
        bg[j][fn] = *(const bf16x8*)&lds[(3 + j) * 4096 + (nb + fn * 16 + fl15) * 32 + kcol];

#pragma unroll
    for (int fm = 0; fm < 4; ++fm)
#pragma unroll
      for (int fn = 0; fn < 4; ++fn) {
        f32x4 a = acc[fm][fn];
        a = __builtin_amdgcn_mfma_f32_16x16x32_bf16(af[0][fm], bg[0][fn], a, 0, 0, 0);
        a = __builtin_amdgcn_mfma_f32_16x16x32_bf16(af[1][fm], bg[0][fn], a, 0, 0, 0);
        a = __builtin_amdgcn_mfma_f32_16x16x32_bf16(af[0][fm], bg[1][fn], a, 0, 0, 0);
        a = __builtin_amdgcn_mfma_f32_16x16x32_bf16(af[2][fm], bg[0][fn], a, 0, 0, 0);
        a = __builtin_amdgcn_mfma_f32_16x16x32_bf16(af[0][fm], bg[2][fn], a, 0, 0, 0);
        a = __builtin_amdgcn_mfma_f32_16x16x32_bf16(af[1][fm], bg[1][fn], a, 0, 0, 0);
        acc[fm][fn] = a;
      }
  }

#pragma unroll
  for (int fm = 0; fm < 4; ++fm) {
    const int lm = bm * 128 + mb + fm * 16 + fq * 4;
#pragma unroll
    for (int fn = 0; fn < 4; ++fn) {
      const int col = bj * 128 + nb + fn * 16 + fl15;
#pragma unroll
      for (int r = 0; r < 4; ++r)
        TILE[(size_t)(lm + r) * CHK + col] = acc[fm][fn][r];
      if (TILT) {
        float4 v = make_float4(acc[fm][fn][0], acc[fm][fn][1], acc[fm][fn][2], acc[fm][fn][3]);
        *(float4*)(TILT + (size_t)col * CHK + lm) = v;
      }
    }
  }
}

// ---------------- K1: chunked row-panel sim (fallback, proven) ----------------
__global__ __launch_bounds__(256) void k_simgemm_mfma(
    const ushort* __restrict__ FH, const ushort* __restrict__ FM, const ushort* __restrict__ FL,
    float* __restrict__ C, int row0) {
  __shared__ ushort lds[6 * 4096];
  const int bj = blockIdx.x;
  const int bm = blockIdx.y;
  const int t = threadIdx.x;
  const int w = t >> 6, l = t & 63;
  const int arow0 = row0 + bm * 128;
  const int brow0 = bj * 128;
  const int segr = l >> 2;
  const int segq = l & 3;
  const int fl15 = l & 15, fq = l >> 4;
  const int wr = w >> 1, wc = w & 1;
  const int mb = wr * 64, nb = wc * 64;

  f32x4 acc[4][4];
#pragma unroll
  for (int i = 0; i < 4; ++i)
#pragma unroll
    for (int j = 0; j < 4; ++j) acc[i][j] = (f32x4){0.f, 0.f, 0.f, 0.f};

  for (int k0 = 0; k0 < DFEAT; k0 += 32) {
    __syncthreads();
#pragma unroll
    for (int c = 0; c < 12; ++c) {
      const int cc = w * 12 + c;
      const int tt = cc >> 3;
      const int p = cc & 7;
      const int rowbase = (tt < 3) ? arow0 : brow0;
      const int sp = (tt < 3) ? tt : (tt - 3);
      const ushort* sel = (sp == 0) ? FH : ((sp == 1) ? FM : FL);
      const ushort* g = sel + (size_t)(rowbase + p * 16 + segr) * DFEAT + (k0 + segq * 8);
      __builtin_amdgcn_global_load_lds((const __attribute__((address_space(1))) unsigned int*)g,
                                       (__attribute__((address_space(3))) unsigned int*)&lds[tt * 4096 + p * 512],
                                       16, 0, 0);
    }
    __syncthreads();

    bf16x8 af[3][4];
    bf16x8 bg[3][4];
    const int kcol = fq * 8;
#pragma unroll
    for (int i = 0; i < 3; ++i)
#pragma unroll
      for (int fm = 0; fm < 4; ++fm)
        af[i][fm] = *(const bf16x8*)&lds[i * 4096 + (mb + fm * 16 + fl15) * 32 + kcol];
#pragma unroll
    for (int j = 0; j < 3; ++j)
#pragma unroll
      for (int fn = 0; fn < 4; ++fn)
        bg[j][fn] = *(const bf16x8*)&lds[(3 + j) * 4096 + (nb + fn * 16 + fl15) * 32 + kcol];

#pragma unroll
    for (int fm = 0; fm < 4; ++fm)
#pragma unroll
      for (int fn = 0; fn < 4; ++fn) {
        f32x4 a = acc[fm][fn];
        a = __builtin_amdgcn_mfma_f32_16x16x32_bf16(af[0][fm], bg[0][fn], a, 0, 0, 0);
        a = __builtin_amdgcn_mfma_f32_16x16x32_bf16(af[1][fm], bg[0][fn], a, 0, 0, 0);
        a = __builtin_amdgcn_mfma_f32_16x16x32_bf16(af[0][fm], bg[1][fn], a, 0, 0, 0);
        a = __builtin_amdgcn_mfma_f32_16x16x32_bf16(af[2][fm], bg[0][fn], a, 0, 0, 0);
        a = __builtin_amdgcn_mfma_f32_16x16x32_bf16(af[0][fm], bg[2][fn], a, 0, 0, 0);
        a = __builtin_amdgcn_mfma_f32_16x16x32_bf16(af[1][fm], bg[1][fn], a, 0, 0, 0);
        acc[fm][fn] = a;
      }
  }

#pragma unroll
  for (int fm = 0; fm < 4; ++fm) {
    const int lm = bm * 128 + mb + fm * 16 + fq * 4;
#pragma unroll
    for (int fn = 0; fn < 4; ++fn) {
      const int col = bj * 128 + nb + fn * 16 + fl15;
#pragma unroll
      for (int r = 0; r < 4; ++r)
        C[(size_t)(lm + r) * NROWS + col] = acc[fm][fn][r];
    }
  }
}

// ---------------- K1b: generic bf16x3 MFMA GEMM: C = A . B^T ----------------
__global__ __launch_bounds__(256) void k_gemm3(const ushort* __restrict__ AH, const ushort* __restrict__ AL,
                                               const ushort* __restrict__ BH, const ushort* __restrict__ BL,
                                               float* __restrict__ C, int K, int N) {
  __shared__ ushort lds[4 * 4096];
  const int bj = blockIdx.x, bm = blockIdx.y;
  const int t = threadIdx.x;
  const int w = t >> 6, l = t & 63;
  const int segr = l >> 2, segq = l & 3;
  const int fl15 = l & 15, fq = l >> 4;
  const int wr = w >> 1, wc = w & 1;
  const int mb = wr * 64, nb = wc * 64;

  f32x4 acc[4][4];
#pragma unroll
  for (int i = 0; i < 4; ++i)
#pragma unroll
    for (int j = 0; j < 4; ++j) acc[i][j] = (f32x4){0.f, 0.f, 0.f, 0.f};

  for (int k0 = 0; k0 < K; k0 += 32) {
    __syncthreads();
#pragma unroll
    for (int c = 0; c < 8; ++c) {
      const int s = w * 8 + c;
      const int tt = s >> 3;
      const int p = s & 7;
      const int rowbase = (tt < 2) ? (bm * 128) : (bj * 128);
      const ushort* sel = (tt == 0) ? AH : ((tt == 1) ? AL : ((tt == 2) ? BH : BL));
      const ushort* g = sel + (size_t)(rowbase + p * 16 + segr) * K + (k0 + segq * 8);
      __builtin_amdgcn_global_load_lds((const __attribute__((address_space(1))) unsigned int*)g,
                                       (__attribute__((address_space(3))) unsigned int*)&lds[s * 512],
                                       16, 0, 0);
    }
    __syncthreads();

    bf16x8 af[2][4];
    bf16x8 bg[2][4];
    const int kcol = fq * 8;
#pragma unroll
    for (int i = 0; i < 2; ++i)
#pragma unroll
      for (int fm = 0; fm < 4; ++fm)
        af[i][fm] = *(const bf16x8*)&lds[i * 4096 + (mb + fm * 16 + fl15) * 32 + kcol];
#pragma unroll
    for (int j = 0; j < 2; ++j)
#pragma unroll
      for (int fn = 0; fn < 4; ++fn)
        bg[j][fn] = *(const bf16x8*)&lds[(2 + j) * 4096 + (nb + fn * 16 + fl15) * 32 + kcol];

#pragma unroll
    for (int fm = 0; fm < 4; ++fm)
#pragma unroll
      for (int fn = 0; fn < 4; ++fn) {
        f32x4 a = acc[fm][fn];
        a = __builtin_amdgcn_mfma_f32_16x16x32_bf16(af[0][fm], bg[0][fn], a, 0, 0, 0);
        a = __builtin_amdgcn_mfma_f32_16x16x32_bf16(af[0][fm], bg[1][fn], a, 0, 0, 0);
        a = __builtin_amdgcn_mfma_f32_16x16x32_bf16(af[1][fm], bg[0][fn], a, 0, 0, 0);
        acc[fm][fn] = a;
      }
  }

#pragma unroll
  for (int fm = 0; fm < 4; ++fm) {
    const int row = bm * 128 + mb + fm * 16 + fq * 4;
#pragma unroll
    for (int fn = 0; fn < 4; ++fn) {
      const int col = bj * 128 + nb + fn * 16 + fl15;
#pragma unroll
      for (int r = 0; r < 4; ++r)
        C[(size_t)(row + r) * N + col] = acc[fm][fn][r];
    }
  }
}

// ---------------- K2i: init running top-k ----------------
__global__ __launch_bounds__(256) void k_init_topk(float* __restrict__ topv, int* __restrict__ topi) {
  const int i = blockIdx.x * 256 + threadIdx.x;
  topv[i] = -INFINITY;
  topi[i] = 0;
}

// ---------------- K2u: merge-update running top-64 (binary-search select + bitonic sort) ----------------
// All 2112 keys (2048 tile + 64 old) are distinct u64s -> 64th-largest T has count(>=T)==64 exactly.
__global__ __launch_bounds__(256) void k_topk_update(const float* __restrict__ T, int rowbase, int colbase,
                                                     float* __restrict__ topv, int* __restrict__ topi) {
  __shared__ unsigned cnt[64];
  __shared__ unsigned nsel;
  __shared__ u64 selbuf[64];
  const int t = threadIdx.x;
  const int row = rowbase + blockIdx.x;
  const float* src = T + (size_t)blockIdx.x * CHK;

  if (t < 64) cnt[t] = 0;
  if (t == 0) nsel = 0;

  u64 k[9];
  int nk = 8;
#pragma unroll
  for (int q = 0; q < 8; ++q) {
    float v = src[t + 256 * q];
    k[q] = mkkey_vi(v, colbase + t + 256 * q);
  }
  k[8] = 0;
  if (t < 64) {
    k[8] = mkkey_vi(topv[(size_t)row * KSEL + t], topi[(size_t)row * KSEL + t]);
    nk = 9;
  }
  __syncthreads();

  // build T64 bit-by-bit: largest threshold with count(keys >= T64) >= 64
  u64 T64 = 0;
  for (int bit = 63; bit >= 0; --bit) {
    const u64 cand = T64 | (1ull << bit);
    unsigned c = 0;
#pragma unroll
    for (int q = 0; q < 9; ++q) c += (q < nk && k[q] >= cand) ? 1u : 0u;
#pragma unroll
    for (int s = 32; s > 0; s >>= 1) c += __shfl_down(c, s);
    if ((t & 63) == 0) atomicAdd(&cnt[bit], c);
    __syncthreads();
    if (cnt[bit] >= 64) T64 = cand;
  }

  // collect exactly-64 keys >= T64
#pragma unroll
  for (int q = 0; q < 9; ++q) {
    if (q < nk && k[q] >= T64) {
      unsigned p = atomicAdd(&nsel, 1u);
      if (p < 64) selbuf[p] = k[q];
    }
  }
  __syncthreads();

  // wave 0: bitonic sort 64 keys descending, write out
  if (t < 64) {
    u64 key = selbuf[t];
#pragma unroll
    for (int kk = 2; kk <= 64; kk <<= 1) {
#pragma unroll
      for (int j = kk >> 1; j > 0; j >>= 1) {
        u64 other = __shfl_xor(key, j);
        const bool dirDesc = ((t & kk) == 0);
        const bool upper = ((t & j) != 0);
        u64 mx = umax64(key, other);
        u64 mn = (key < other) ? key : other;
        key = (dirDesc ^ upper) ? mx : mn;
      }
    }
    const unsigned ui = (unsigned)(key >> 32);
    const float v = __uint_as_float((ui & 0x80000000u) ? (ui ^ 0x80000000u) : ~ui);
    const int idx = (int)(0xFFFFFFFFu - (unsigned)(key & 0xFFFFFFFFull));
    topv[(size_t)row * KSEL + t] = v;
    topi[(size_t)row * KSEL + t] = idx;
  }
}

// ---------------- K2e: exps from final top-10 ----------------
__global__ __launch_bounds__(256) void k_exps(const float* __restrict__ topv, float* __restrict__ exps) {
  const int r = blockIdx.x * 256 + threadIdx.x;
  float s = 0.f;
#pragma unroll
  for (int q = 0; q < 10; ++q) s += topv[(size_t)r * KSEL + q];
  exps[r] = expf(s / 40.0f);
}

// ---------------- K2: full-row top-64 (fallback path) ----------------
__global__ __launch_bounds__(256) void k_topk(const float* __restrict__ simc,
                                              float* __restrict__ topv, int* __restrict__ topi,
                                              float* __restrict__ exps, int row0) {
  __shared__ float vals[NROWS];
  __shared__ u64 wmax[4];
  __shared__ float outv[KSEL];
  __shared__ int outi[KSEL];
  const int row = row0 + blockIdx.x;
  const int t = threadIdx.x;
  const float* src = simc + (size_t)blockIdx.x * NROWS;
  for (int i = t; i < NROWS; i += 256) vals[i] = src[i];
  __syncthreads();

  u64 lk = 0;
#pragma unroll
  for (int m = 0; m < 32; ++m) {
    int i = t + 256 * m;
    lk = umax64(lk, mkkey_vi(vals[i], i));
  }

  const int lane = t & 63, wv = t >> 6;
  for (int it = 0; it < KSEL; ++it) {
    u64 wk = lk;
#pragma unroll
    for (int s = 32; s > 0; s >>= 1) {
      u64 o = __shfl_xor(wk, s);
      wk = umax64(wk, o);
    }
    if (lane == 0) wmax[wv] = wk;
    __syncthreads();
    u64 g = umax64(umax64(wmax[0], wmax[1]), umax64(wmax[2], wmax[3]));
    const unsigned ui = (unsigned)(g >> 32);
    const float v = __uint_as_float((ui & 0x80000000u) ? (ui ^ 0x80000000u) : ~ui);
    const int idx = (int)(0xFFFFFFFFu - (unsigned)(g & 0xFFFFFFFFull));
    if (t == 0) { outv[it] = v; outi[it] = idx; }
    if (t == (idx & 255)) {
      vals[idx] = -INFINITY;
      u64 nl = 0;
#pragma unroll
      for (int m = 0; m < 32; ++m) {
        int i = t + 256 * m;
        nl = umax64(nl, mkkey_vi(vals[i], i));
      }
      lk = nl;
    }
    __syncthreads();
  }
  if (t < KSEL) {
    topv[(size_t)row * KSEL + t] = outv[t];
    topi[(size_t)row * KSEL + t] = outi[t];
  }
  if (t == 0) {
    float s = 0.f;
#pragma unroll
    for (int q = 0; q < 10; ++q) s += outv[q];
    exps[row] = expf(s / 40.0f);
  }
}

// ---------------- K3: adjacency build + row softmax ----------------
__global__ __launch_bounds__(256) void k_adj(const int* __restrict__ indexes,
                                             const float* __restrict__ topv, const int* __restrict__ topi,
                                             const float* __restrict__ exps, float* __restrict__ adj) {
  __shared__ int nbr[64];
  __shared__ int neigh[64][10];
  __shared__ float tv[64][10];
  __shared__ float adjL[64][64];
  const int b = blockIdx.x;
  const int t = threadIdx.x;
  const int idx = indexes[b];
  if (t < 64) nbr[t] = topi[(size_t)idx * KSEL + t];
  __syncthreads();
  for (int p = t; p < 640; p += 256) {
    const int r = p / 10, q = p - r * 10;
    const int m = nbr[r];
    const int c = topi[(size_t)m * KSEL + q];
    neigh[r][q] = c;
    tv[r][q] = topv[(size_t)m * KSEL + q] * exps[c];
  }
  __syncthreads();
  for (int p = t; p < 4096; p += 256) {
    const int i = p >> 6, j = p & 63;
    float s = 0.f;
#pragma unroll
    for (int q = 0; q < 10; ++q) {
      const int c = neigh[i][q];
      float add = 0.f;
      for (int s2 = 0; s2 < 10; ++s2) {
        if (neigh[j][s2] == c) { add = (tv[j][s2] > 0.f) ? tv[i][q] : 0.f; break; }
      }
      s += add;
    }
    adjL[i][j] = s;
  }
  __syncthreads();
  const int wv = t >> 6, lane = t & 63;
  for (int i = wv * 16; i < wv * 16 + 16; ++i) {
    float v = adjL[i][lane];
    float mx = v;
#pragma unroll
    for (int s = 32; s > 0; s >>= 1) mx = fmaxf(mx, __shfl_xor(mx, s));
    float e = expf(v - mx);
    float sum = e;
#pragma unroll
    for (int s = 32; s > 0; s >>= 1) sum += __shfl_xor(sum, s);
    adj[((size_t)b * 64 + i) * 64 + lane] = e / sum;
  }
}

// ---------------- K4: xs splits ----------------
__global__ __launch_bounds__(256) void k_xs_split(const int* __restrict__ indexes, const int* __restrict__ topi,
                                                  const float* __restrict__ F,
                                                  ushort* __restrict__ XH, ushort* __restrict__ XL) {
  const int b = blockIdx.y, r = blockIdx.x;
  const int t = threadIdx.x;
  const int idx = indexes[b];
  const int m  = topi[(size_t)idx * KSEL + r];
  const int m0 = topi[(size_t)idx * KSEL + 0];
  const float4* pa = (const float4*)(F + (size_t)m * DFEAT);
  const float4* pb = (const float4*)(F + (size_t)m0 * DFEAT);
  const size_t rowoff = ((size_t)b * 64 + r) * DFEAT;
#pragma unroll
  for (int it = 0; it < 2; ++it) {
    const int i = t + it * 256;
    float4 a = pa[i], c = pb[i];
    float d[4] = {a.x - c.x, a.y - c.y, a.z - c.z, a.w - c.w};
    ushort h[4], l[4];
#pragma unroll
    for (int q = 0; q < 4; ++q) split2(d[q], h[q], l[q]);
    ushort4 vh = {h[0], h[1], h[2], h[3]};
    ushort4 vl = {l[0], l[1], l[2], l[3]};
    *(ushort4*)(XH + rowoff + i * 4) = vh;
    *(ushort4*)(XL + rowoff + i * 4) = vl;
  }
}

// ---------------- K5: weight pre-split, transposed + combined ----------------
__global__ __launch_bounds__(256) void k_wsplitT(const float* __restrict__ W,
                                                 ushort* __restrict__ WTH, ushort* __restrict__ WTL,
                                                 int K, int F) {
  __shared__ float tile[32][33];
  const int k0 = blockIdx.x * 32;
  const int n0 = blockIdx.y * 32;
  const int t = threadIdx.x;
  {
    const int r = t >> 3, cq = t & 7;
    const int srcRow = (n0 < F) ? (k0 + r) : (K + k0 + r);
    const int srcCol = (n0 < F) ? n0 : (n0 - F);
    float4 v = *(const float4*)(W + (size_t)srcRow * F + srcCol + cq * 4);
    tile[r][cq * 4 + 0] = v.x; tile[r][cq * 4 + 1] = v.y;
    tile[r][cq * 4 + 2] = v.z; tile[r][cq * 4 + 3] = v.w;
  }
  __syncthreads();
  {
    const int nl = t >> 3, kq = t & 7;
    ushort h[4], l[4];
#pragma unroll
    for (int i = 0; i < 4; ++i) split2(tile[kq * 4 + i][nl], h[i], l[i]);
    ushort4 vh = {h[0], h[1], h[2], h[3]};
    ushort4 vl = {l[0], l[1], l[2], l[3]};
    *(ushort4*)(WTH + (size_t)(n0 + nl) * K + k0 + kq * 4) = vh;
    *(ushort4*)(WTL + (size_t)(n0 + nl) * K + k0 + kq * 4) = vl;
  }
}

// ---------------- K6: layer epilogue ----------------
__global__ __launch_bounds__(256) void k_postlayer(const float* __restrict__ C, const float* __restrict__ adj,
                                                   const float* __restrict__ bias,
                                                   ushort* __restrict__ HH, ushort* __restrict__ HL, int F) {
  __shared__ float adjL[64 * 65];
  __shared__ float QL[64 * 66];
  const int f0 = blockIdx.x * 64;
  const int b = blockIdx.y;
  const int t = threadIdx.x;
  const int fc = t & 63, rg = t >> 6;
  const int twoF = 2 * F;
  for (int i = t; i < 4096; i += 256) {
    const int r = i >> 6, j = i & 63;
    adjL[r * 65 + j] = adj[(size_t)b * 4096 + i];
    QL[r * 66 + j] = C[(size_t)(b * 64 + r) * twoF + F + f0 + j];
  }
  __syncthreads();
  const float bv = bias[f0 + fc];
  for (int rr = 0; rr < 16; ++rr) {
    const int r = rg * 16 + rr;
    float s = 0.f;
#pragma unroll 8
    for (int j0 = 0; j0 < 64; ++j0) {
      const int j = (j0 + fc) & 63;
      s += adjL[r * 65 + j] * QL[j * 66 + fc];
    }
    const int row = b * 64 + r;
    float h = C[(size_t)row * twoF + f0 + fc] + s + bv;
    h = fmaxf(h, 0.f);
    ushort hh, hl;
    split2(h, hh, hl);
    HH[(size_t)row * F + f0 + fc] = hh;
    HL[(size_t)row * F + f0 + fc] = hl;
  }
}

// ---------------- K7: classifier epilogue ----------------
__global__ __launch_bounds__(256) void k_postcls(const float* __restrict__ C, const float* __restrict__ bias,
                                                 const float* __restrict__ pre, float* __restrict__ HC) {
  const size_t i0 = ((size_t)blockIdx.x * 256 + threadIdx.x) * 4;
  const int col = (int)(i0 & 255);
  float4 c = *(const float4*)(C + i0);
  float o[4] = {c.x, c.y, c.z, c.w};
#pragma unroll
  for (int i = 0; i < 4; ++i) {
    float h = o[i] + bias[col + i];
    o[i] = (h > 0.f) ? h : pre[col + i] * h;
  }
  *(float4*)(HC + i0) = make_float4(o[0], o[1], o[2], o[3]);
}

// ---------------- K8: pred = HC @ Wc2 + bc2 ----------------
__global__ __launch_bounds__(256) void k_final(const float* __restrict__ Hc, const float* __restrict__ Wc2,
                                               const float* __restrict__ bc2, float* __restrict__ outp) {
  __shared__ float w[512];
  __shared__ float red[512];
  const int t = threadIdx.x;
  for (int i = t; i < 512; i += 256) w[i] = Wc2[i];
  __syncthreads();
  const int m = blockIdx.x * 64 + (t >> 2);
  const int p = t & 3;
  const float* h = Hc + (size_t)m * 256;
  float s0 = 0.f, s1 = 0.f;
  for (int k = p * 64; k < p * 64 + 64; ++k) {
    float hv = h[k];
    s0 += hv * w[k * 2];
    s1 += hv * w[k * 2 + 1];
  }
  red[t * 2] = s0; red[t * 2 + 1] = s1;
  __syncthreads();
  if (p == 0) {
    for (int q = 1; q < 4; ++q) { s0 += red[(t + q) * 2]; s1 += red[(t + q) * 2 + 1]; }
    outp[m * 2 + 0] = s0 + bc2[0];
    outp[m * 2 + 1] = s1 + bc2[1];
  }
}

extern "C" void kernel_launch(void* const* d_in, const int* in_sizes, int n_in,
                              void* d_out, int out_size, void* d_ws, size_t ws_size,
                              hipStream_t stream) {
  const int*   indexes = (const int*)d_in[0];
  const float* F   = (const float*)d_in[1];
  const float* W1  = (const float*)d_in[4];
  const float* b1  = (const float*)d_in[5];
  const float* W2  = (const float*)d_in[6];
  const float* b2  = (const float*)d_in[7];
  const float* W3  = (const float*)d_in[8];
  const float* b3  = (const float*)d_in[9];
  const float* W4  = (const float*)d_in[10];
  const float* b4  = (const float*)d_in[11];
  const float* Wc1 = (const float*)d_in[12];
  const float* bc1 = (const float*)d_in[13];
  const float* pre = (const float*)d_in[14];
  const float* Wc2 = (const float*)d_in[15];
  const float* bc2 = (const float*)d_in[16];
  float* out = (float*)d_out;

  size_t off = 0;
  auto take = [&](size_t bytes) -> char* {
    char* q = (char*)d_ws + off;
    off += (bytes + 255) & ~(size_t)255;
    return q;
  };
  float* TOPV = (float*)take((size_t)NROWS * KSEL * 4);
  int*   TOPI = (int*)  take((size_t)NROWS * KSEL * 4);
  float* EXPS = (float*)take((size_t)NROWS * 4);
  float* ADJ  = (float*)take((size_t)64 * 64 * 64 * 4);
  char*  big  = (char*)d_ws + off;
  const size_t big_bytes = (ws_size > off) ? (ws_size - off) : 0;

  const size_t Mi = 1024 * 1024;
  const size_t Ki = 1024;
  const size_t splitBytes = (size_t)NROWS * DFEAT * 2;

  if (big_bytes >= 160 * Mi) {
    ushort* FH = (ushort*)big;
    ushort* FM = (ushort*)(big + splitBytes);
    ushort* FL = (ushort*)(big + 2 * splitBytes);
    float* TILE0  = (float*)(big + 96 * Mi);
    float* TILE0T = (float*)(big + 112 * Mi);
    float* TILE1  = (float*)(big + 128 * Mi);
    float* TILE1T = (float*)(big + 144 * Mi);
    k_split<<<NROWS * DFEAT / 1024, 256, 0, stream>>>(F, FH, FM, FL);
    k_init_topk<<<NROWS * KSEL / 256, 256, 0, stream>>>(TOPV, TOPI);
    const int pairs[10][2] = {{0,0},{0,1},{0,2},{0,3},{1,1},{1,2},{1,3},{2,2},{2,3},{3,3}};
    for (int b = 0; b < 5; ++b) {
      const int ia = pairs[2*b][0],   ja = pairs[2*b][1];
      const int ib = pairs[2*b+1][0], jb = pairs[2*b+1][1];
      k_simgemm_pair<<<dim3(16, 16, 2), 256, 0, stream>>>(
          FH, FM, FL,
          TILE0, (ia != ja) ? TILE0T : nullptr, ia, ja,
          TILE1, (ib != jb) ? TILE1T : nullptr, ib, jb);
      k_topk_update<<<CHK, 256, 0, stream>>>(TILE0, ia * CHK, ja * CHK, TOPV, TOPI);
      if (ia != ja) k_topk_update<<<CHK, 256, 0, stream>>>(TILE0T, ja * CHK, ia * CHK, TOPV, TOPI);
      k_topk_update<<<CHK, 256, 0, stream>>>(TILE1, ib * CHK, jb * CHK, TOPV, TOPI);
      if (ib != jb) k_topk_update<<<CHK, 256, 0, stream>>>(TILE1T, jb * CHK, ib * CHK, TOPV, TOPI);
    }
    k_exps<<<NROWS / 256, 256, 0, stream>>>(TOPV, EXPS);
  } else {
    int fchunk = 0;
    for (int c = 2048; c >= 512; c >>= 1) {
      if (3 * splitBytes + (size_t)c * NROWS * 4 <= big_bytes) { fchunk = c; break; }
    }
    if (fchunk == 0) {
      hipMemsetAsync(d_out, 0, (size_t)out_size * 4, stream);
      return;
    }
    ushort* FH = (ushort*)big;
    ushort* FM = (ushort*)(big + splitBytes);
    ushort* FL = (ushort*)(big + 2 * splitBytes);
    float* SIMC = (float*)(big + 3 * splitBytes);
    k_split<<<NROWS * DFEAT / 1024, 256, 0, stream>>>(F, FH, FM, FL);
    for (int r0 = 0; r0 < NROWS; r0 += fchunk) {
      k_simgemm_mfma<<<dim3(64, fchunk / 128), 256, 0, stream>>>(FH, FM, FL, SIMC, r0);
      k_topk<<<fchunk, 256, 0, stream>>>(SIMC, TOPV, TOPI, EXPS, r0);
    }
  }
  k_adj<<<64, 256, 0, stream>>>(indexes, TOPV, TOPI, EXPS, ADJ);

  ushort* XH   = (ushort*)(big);
  ushort* XL   = (ushort*)(big + 16 * Mi);
  ushort* WT1H = (ushort*)(big + 32 * Mi);
  ushort* WT1L = (ushort*)(big + 40 * Mi);
  ushort* WT2H = (ushort*)(big + 48 * Mi);
  ushort* WT2L = (ushort*)(big + 50 * Mi);
  ushort* WT3H = (ushort*)(big + 52 * Mi);
  ushort* WT3L = (ushort*)(big + 52 * Mi + 512 * Ki);
  ushort* WT4H = (ushort*)(big + 53 * Mi);
  ushort* WT4L = (ushort*)(big + 53 * Mi + 256 * Ki);
  ushort* WTcH = (ushort*)(big + 53 * Mi + 512 * Ki);
  ushort* WTcL = (ushort*)(big + 53 * Mi + 640 * Ki);
  float*  CBUF = (float*)(big + 54 * Mi);
  float*  HC   = (float*)(big + 86 * Mi);
  ushort* H1H  = (ushort*)(big + 32 * Mi);
  ushort* H1L  = (ushort*)(big + 40 * Mi);
  ushort* H2H  = (ushort*)(big);
  ushort* H2L  = (ushort*)(big + 4 * Mi);
  ushort* H3H  = (ushort*)(big + 8 * Mi);
  ushort* H3L  = (ushort*)(big + 10 * Mi);
  ushort* H4H  = (ushort*)(big + 12 * Mi);
  ushort* H4L  = (ushort*)(big + 14 * Mi);

  k_wsplitT<<<dim3(2048 / 32, 2048 / 32), 256, 0, stream>>>(W1, WT1H, WT1L, 2048, 1024);
  k_wsplitT<<<dim3(1024 / 32, 1024 / 32), 256, 0, stream>>>(W2, WT2H, WT2L, 1024, 512);
  k_wsplitT<<<dim3(512 / 32, 512 / 32), 256, 0, stream>>>(W3, WT3H, WT3L, 512, 256);
  k_wsplitT<<<dim3(256 / 32, 512 / 32), 256, 0, stream>>>(W4, WT4H, WT4L, 256, 256);
  k_wsplitT<<<dim3(256 / 32, 256 / 32), 256, 0, stream>>>(Wc1, WTcH, WTcL, 256, 256);

  k_xs_split<<<dim3(64, 64), 256, 0, stream>>>(indexes, TOPI, F, XH, XL);

  k_gemm3<<<dim3(16, 32), 256, 0, stream>>>(XH, XL, WT1H, WT1L, CBUF, 2048, 2048);
  k_postlayer<<<dim3(16, 64), 256, 0, stream>>>(CBUF, ADJ, b1, H1H, H1L, 1024);
  k_gemm3<<<dim3(8, 32), 256, 0, stream>>>(H1H, H1L, WT2H, WT2L, CBUF, 1024, 1024);
  k_postlayer<<<dim3(8, 64), 256, 0, stream>>>(CBUF, ADJ, b2, H2H, H2L, 512);
  k_gemm3<<<dim3(4, 32), 256, 0, stream>>>(H2H, H2L, WT3H, WT3L, CBUF, 512, 512);
  k_postlayer<<<dim3(4, 64), 256, 0, stream>>>(CBUF, ADJ, b3, H3H, H3L, 256);
  k_gemm3<<<dim3(4, 32), 256, 0, stream>>>(H3H, H3L, WT4H, WT4L, CBUF, 256, 512);
  k_postlayer<<<dim3(4, 64), 256, 0, stream>>>(CBUF, ADJ, b4, H4H, H4L, 256);
  k_gemm3<<<dim3(2, 32), 256, 0, stream>>>(H4H, H4L, WTcH, WTcL, CBUF, 256, 256);
  k_postcls<<<4096 * 256 / 1024, 256, 0, stream>>>(CBUF, bc1, pre, HC);

  k_final<<<64, 256, 0, stream>>>(HC, Wc2, bc2, out);
}

// Round 8
// 2207.794 us; speedup vs baseline: 1.5931x; 1.0063x over previous
//
#include <hip/hip_runtime.h>
#include <hip/hip_bf16.h>
#include <math.h>

#define NROWS 8192
#define DFEAT 2048
#define KSEL  64
#define CHK   2048   // symmetric pair chunk

typedef unsigned long long u64;
typedef __attribute__((ext_vector_type(8))) short bf16x8;
typedef __attribute__((ext_vector_type(4))) float f32x4;

__device__ __forceinline__ u64 umax64(u64 a, u64 b) { return a > b ? a : b; }

__device__ __forceinline__ void split2(float v, ushort& h, ushort& l) {
  __hip_bfloat16 bh = __float2bfloat16(v);
  float r = v - __bfloat162float(bh);
  __hip_bfloat16 bl = __float2bfloat16(r);
  h = *(ushort*)&bh; l = *(ushort*)&bl;
}

__device__ __forceinline__ u64 mkkey_vi(float v, int i) {
  unsigned u = __float_as_uint(v);
  u = ((int)u < 0) ? ~u : (u | 0x80000000u);
  return ((u64)u << 32) | (u64)(0xFFFFFFFFu - (unsigned)i);
}

// ---------------- K0: 3-way bf16 split of F (exact to 2^-27) ----------------
__global__ __launch_bounds__(256) void k_split(const float* __restrict__ F, ushort* __restrict__ H,
                                               ushort* __restrict__ M, ushort* __restrict__ L) {
  const size_t i0 = ((size_t)blockIdx.x * 256 + threadIdx.x) * 4;
  float4 x = *(const float4*)(F + i0);
  float xs[4] = {x.x, x.y, x.z, x.w};
  ushort h[4], m[4], l[4];
#pragma unroll
  for (int c = 0; c < 4; ++c) {
    float v = xs[c];
    __hip_bfloat16 bh = __float2bfloat16(v);
    float r1 = v - __bfloat162float(bh);
    __hip_bfloat16 bm = __float2bfloat16(r1);
    float r2 = r1 - __bfloat162float(bm);
    __hip_bfloat16 bl = __float2bfloat16(r2);
    h[c] = *(ushort*)&bh; m[c] = *(ushort*)&bm; l[c] = *(ushort*)&bl;
  }
  ushort4 vh = {h[0], h[1], h[2], h[3]};
  ushort4 vm = {m[0], m[1], m[2], m[3]};
  ushort4 vl = {l[0], l[1], l[2], l[3]};
  *(ushort4*)(H + i0) = vh;
  *(ushort4*)(M + i0) = vm;
  *(ushort4*)(L + i0) = vl;
}

// ---------------- K1p: symmetric pair tile GEMM (bf16x6), 2 pairs per launch ----------------
// LDS tiles [128][32] bf16 with k-slot XOR swizzle: LDS[r][s] holds global slot s^((r>>1)&3).
// Staging pre-swizzles the GLOBAL source (global_load_lds dest is linear); reads use matching XOR.
__global__ __launch_bounds__(256) void k_simgemm_pair(
    const ushort* __restrict__ FH, const ushort* __restrict__ FM, const ushort* __restrict__ FL,
    float* __restrict__ T0, float* __restrict__ T0T, int i0, int j0,
    float* __restrict__ T1, float* __restrict__ T1T, int i1, int j1) {
  __shared__ ushort lds[6 * 4096];
  const int z = blockIdx.z;
  float* TILE = z ? T1 : T0;
  float* TILT = z ? T1T : T0T;
  const int ci = z ? i1 : i0;
  const int cj = z ? j1 : j0;
  const int bj = blockIdx.x;
  const int bm = blockIdx.y;
  const int t = threadIdx.x;
  const int w = t >> 6, l = t & 63;
  const int arow0 = ci * CHK + bm * 128;
  const int brow0 = cj * CHK + bj * 128;
  const int segr = l >> 2;
  const int segq_s = (l & 3) ^ ((l >> 3) & 3);   // swizzled k-slot for staging
  const int fl15 = l & 15, fq = l >> 4;
  const int kswz = (fq ^ ((fl15 >> 1) & 3)) * 8; // swizzled k-slot for reads (ushort idx)
  const int wr = w >> 1, wc = w & 1;
  const int mb = wr * 64, nb = wc * 64;

  f32x4 acc[4][4];
#pragma unroll
  for (int i = 0; i < 4; ++i)
#pragma unroll
    for (int j = 0; j < 4; ++j) acc[i][j] = (f32x4){0.f, 0.f, 0.f, 0.f};

  for (int k0 = 0; k0 < DFEAT; k0 += 32) {
    __syncthreads();
#pragma unroll
    for (int c = 0; c < 12; ++c) {
      const int cc = w * 12 + c;
      const int tt = cc >> 3;
      const int p = cc & 7;
      const int rowbase = (tt < 3) ? arow0 : brow0;
      const int sp = (tt < 3) ? tt : (tt - 3);
      const ushort* sel = (sp == 0) ? FH : ((sp == 1) ? FM : FL);
      const ushort* g = sel + (size_t)(rowbase + p * 16 + segr) * DFEAT + (k0 + segq_s * 8);
      __builtin_amdgcn_global_load_lds((const __attribute__((address_space(1))) unsigned int*)g,
                                       (__attribute__((address_space(3))) unsigned int*)&lds[tt * 4096 + p * 512],
                                       16, 0, 0);
    }
    __syncthreads();

    bf16x8 af[3][4];
    bf16x8 bg[3][4];
#pragma unroll
    for (int i = 0; i < 3; ++i)
#pragma unroll
      for (int fm = 0; fm < 4; ++fm)
        af[i][fm] = *(const bf16x8*)&lds[i * 4096 + (mb + fm * 16 + fl15) * 32 + kswz];
#pragma unroll
    for (int j = 0; j < 3; ++j)
#pragma unroll
      for (int fn = 0; fn < 4; ++fn)
        bg[j][fn] = *(const bf16x8*)&lds[(3 + j) * 4096 + (nb + fn * 16 + fl15) * 32 + kswz];

#pragma unroll
    for (int fm = 0; fm < 4; ++fm)
#pragma unroll
      for (int fn = 0; fn < 4; ++fn) {
        f32x4 a = acc[fm][fn];
        a = __builtin_amdgcn_mfma_f32_16x16x32_bf16(af[0][fm], bg[0][fn], a, 0, 0, 0);
        a = __builtin_amdgcn_mfma_f32_16x16x32_bf16(af[1][fm], bg[0][fn], a, 0, 0, 0);
        a = __builtin_amdgcn_mfma_f32_16x16x32_bf16(af[0][fm], bg[1][fn], a, 0, 0, 0);
        a = __builtin_amdgcn_mfma_f32_16x16x32_bf16(af[2][fm], bg[0][fn], a, 0, 0, 0);
        a = __builtin_amdgcn_mfma_f32_16x16x32_bf16(af[0][fm], bg[2][fn], a, 0, 0, 0);
        a = __builtin_amdgcn_mfma_f32_16x16x32_bf16(af[1][fm], bg[1][fn], a, 0, 0, 0);
        acc[fm][fn] = a;
      }
  }

#pragma unroll
  for (int fm = 0; fm < 4; ++fm) {
    const int lm = bm * 128 + mb + fm * 16 + fq * 4;
#pragma unroll
    for (int fn = 0; fn < 4; ++fn) {
      const int col = bj * 128 + nb + fn * 16 + fl15;
#pragma unroll
      for (int r = 0; r < 4; ++r)
        TILE[(size_t)(lm + r) * CHK + col] = acc[fm][fn][r];
      if (TILT) {
        float4 v = make_float4(acc[fm][fn][0], acc[fm][fn][1], acc[fm][fn][2], acc[fm][fn][3]);
        *(float4*)(TILT + (size_t)col * CHK + lm) = v;
      }
    }
  }
}

// ---------------- K1: chunked row-panel sim (fallback, proven, unswizzled) ----------------
__global__ __launch_bounds__(256) void k_simgemm_mfma(
    const ushort* __restrict__ FH, const ushort* __restrict__ FM, const ushort* __restrict__ FL,
    float* __restrict__ C, int row0) {
  __shared__ ushort lds[6 * 4096];
  const int bj = blockIdx.x;
  const int bm = blockIdx.y;
  const int t = threadIdx.x;
  const int w = t >> 6, l = t & 63;
  const int arow0 = row0 + bm * 128;
  const int brow0 = bj * 128;
  const int segr = l >> 2;
  const int segq = l & 3;
  const int fl15 = l & 15, fq = l >> 4;
  const int wr = w >> 1, wc = w & 1;
  const int mb = wr * 64, nb = wc * 64;

  f32x4 acc[4][4];
#pragma unroll
  for (int i = 0; i < 4; ++i)
#pragma unroll
    for (int j = 0; j < 4; ++j) acc[i][j] = (f32x4){0.f, 0.f, 0.f, 0.f};

  for (int k0 = 0; k0 < DFEAT; k0 += 32) {
    __syncthreads();
#pragma unroll
    for (int c = 0; c < 12; ++c) {
      const int cc = w * 12 + c;
      const int tt = cc >> 3;
      const int p = cc & 7;
      const int rowbase = (tt < 3) ? arow0 : brow0;
      const int sp = (tt < 3) ? tt : (tt - 3);
      const ushort* sel = (sp == 0) ? FH : ((sp == 1) ? FM : FL);
      const ushort* g = sel + (size_t)(rowbase + p * 16 + segr) * DFEAT + (k0 + segq * 8);
      __builtin_amdgcn_global_load_lds((const __attribute__((address_space(1))) unsigned int*)g,
                                       (__attribute__((address_space(3))) unsigned int*)&lds[tt * 4096 + p * 512],
                                       16, 0, 0);
    }
    __syncthreads();

    bf16x8 af[3][4];
    bf16x8 bg[3][4];
    const int kcol = fq * 8;
#pragma unroll
    for (int i = 0; i < 3; ++i)
#pragma unroll
      for (int fm = 0; fm < 4; ++fm)
        af[i][fm] = *(const bf16x8*)&lds[i * 4096 + (mb + fm * 16 + fl15) * 32 + kcol];
#pragma unroll
    for (int j = 0; j < 3; ++j)
#pragma unroll
      for (int fn = 0; fn < 4; ++fn)
        bg[j][fn] = *(const bf16x8*)&lds[(3 + j) * 4096 + (nb + fn * 16 + fl15) * 32 + kcol];

#pragma unroll
    for (int fm = 0; fm < 4; ++fm)
#pragma unroll
      for (int fn = 0; fn < 4; ++fn) {
        f32x4 a = acc[fm][fn];
        a = __builtin_amdgcn_mfma_f32_16x16x32_bf16(af[0][fm], bg[0][fn], a, 0, 0, 0);
        a = __builtin_amdgcn_mfma_f32_16x16x32_bf16(af[1][fm], bg[0][fn], a, 0, 0, 0);
        a = __builtin_amdgcn_mfma_f32_16x16x32_bf16(af[0][fm], bg[1][fn], a, 0, 0, 0);
        a = __builtin_amdgcn_mfma_f32_16x16x32_bf16(af[2][fm], bg[0][fn], a, 0, 0, 0);
        a = __builtin_amdgcn_mfma_f32_16x16x32_bf16(af[0][fm], bg[2][fn], a, 0, 0, 0);
        a = __builtin_amdgcn_mfma_f32_16x16x32_bf16(af[1][fm], bg[1][fn], a, 0, 0, 0);
        acc[fm][fn] = a;
      }
  }

#pragma unroll
  for (int fm = 0; fm < 4; ++fm) {
    const int lm = bm * 128 + mb + fm * 16 + fq * 4;
#pragma unroll
    for (int fn = 0; fn < 4; ++fn) {
      const int col = bj * 128 + nb + fn * 16 + fl15;
#pragma unroll
      for (int r = 0; r < 4; ++r)
        C[(size_t)(lm + r) * NROWS + col] = acc[fm][fn][r];
    }
  }
}

// ---------------- K1b: generic bf16x3 MFMA GEMM: C = A . B^T (swizzled LDS) ----------------
__global__ __launch_bounds__(256) void k_gemm3(const ushort* __restrict__ AH, const ushort* __restrict__ AL,
                                               const ushort* __restrict__ BH, const ushort* __restrict__ BL,
                                               float* __restrict__ C, int K, int N) {
  __shared__ ushort lds[4 * 4096];
  const int bj = blockIdx.x, bm = blockIdx.y;
  const int t = threadIdx.x;
  const int w = t >> 6, l = t & 63;
  const int segr = l >> 2;
  const int segq_s = (l & 3) ^ ((l >> 3) & 3);
  const int fl15 = l & 15, fq = l >> 4;
  const int kswz = (fq ^ ((fl15 >> 1) & 3)) * 8;
  const int wr = w >> 1, wc = w & 1;
  const int mb = wr * 64, nb = wc * 64;

  f32x4 acc[4][4];
#pragma unroll
  for (int i = 0; i < 4; ++i)
#pragma unroll
    for (int j = 0; j < 4; ++j) acc[i][j] = (f32x4){0.f, 0.f, 0.f, 0.f};

  for (int k0 = 0; k0 < K; k0 += 32) {
    __syncthreads();
#pragma unroll
    for (int c = 0; c < 8; ++c) {
      const int s = w * 8 + c;
      const int tt = s >> 3;
      const int p = s & 7;
      const int rowbase = (tt < 2) ? (bm * 128) : (bj * 128);
      const ushort* sel = (tt == 0) ? AH : ((tt == 1) ? AL : ((tt == 2) ? BH : BL));
      const ushort* g = sel + (size_t)(rowbase + p * 16 + segr) * K + (k0 + segq_s * 8);
      __builtin_amdgcn_global_load_lds((const __attribute__((address_space(1))) unsigned int*)g,
                                       (__attribute__((address_space(3))) unsigned int*)&lds[s * 512],
                                       16, 0, 0);
    }
    __syncthreads();

    bf16x8 af[2][4];
    bf16x8 bg[2][4];
#pragma unroll
    for (int i = 0; i < 2; ++i)
#pragma unroll
      for (int fm = 0; fm < 4; ++fm)
        af[i][fm] = *(const bf16x8*)&lds[i * 4096 + (mb + fm * 16 + fl15) * 32 + kswz];
#pragma unroll
    for (int j = 0; j < 2; ++j)
#pragma unroll
      for (int fn = 0; fn < 4; ++fn)
        bg[j][fn] = *(const bf16x8*)&lds[(2 + j) * 4096 + (nb + fn * 16 + fl15) * 32 + kswz];

#pragma unroll
    for (int fm = 0; fm < 4; ++fm)
#pragma unroll
      for (int fn = 0; fn < 4; ++fn) {
        f32x4 a = acc[fm][fn];
        a = __builtin_amdgcn_mfma_f32_16x16x32_bf16(af[0][fm], bg[0][fn], a, 0, 0, 0);
        a = __builtin_amdgcn_mfma_f32_16x16x32_bf16(af[0][fm], bg[1][fn], a, 0, 0, 0);
        a = __builtin_amdgcn_mfma_f32_16x16x32_bf16(af[1][fm], bg[0][fn], a, 0, 0, 0);
        acc[fm][fn] = a;
      }
  }

#pragma unroll
  for (int fm = 0; fm < 4; ++fm) {
    const int row = bm * 128 + mb + fm * 16 + fq * 4;
#pragma unroll
    for (int fn = 0; fn < 4; ++fn) {
      const int col = bj * 128 + nb + fn * 16 + fl15;
#pragma unroll
      for (int r = 0; r < 4; ++r)
        C[(size_t)(row + r) * N + col] = acc[fm][fn][r];
    }
  }
}

// ---------------- K2i: init running top-k ----------------
__global__ __launch_bounds__(256) void k_init_topk(float* __restrict__ topv, int* __restrict__ topi) {
  const int i = blockIdx.x * 256 + threadIdx.x;
  topv[i] = -INFINITY;
  topi[i] = 0;
}

// ---------------- K2u: merge-update running top-64 (binary-search select + bitonic sort) ----------------
__global__ __launch_bounds__(256) void k_topk_update(const float* __restrict__ T, int rowbase, int colbase,
                                                     float* __restrict__ topv, int* __restrict__ topi) {
  __shared__ unsigned cnt[64];
  __shared__ unsigned nsel;
  __shared__ u64 selbuf[64];
  const int t = threadIdx.x;
  const int row = rowbase + blockIdx.x;
  const float* src = T + (size_t)blockIdx.x * CHK;

  if (t < 64) cnt[t] = 0;
  if (t == 0) nsel = 0;

  u64 k[9];
  int nk = 8;
#pragma unroll
  for (int q = 0; q < 8; ++q) {
    float v = src[t + 256 * q];
    k[q] = mkkey_vi(v, colbase + t + 256 * q);
  }
  k[8] = 0;
  if (t < 64) {
    k[8] = mkkey_vi(topv[(size_t)row * KSEL + t], topi[(size_t)row * KSEL + t]);
    nk = 9;
  }
  __syncthreads();

  u64 T64 = 0;
  for (int bit = 63; bit >= 0; --bit) {
    const u64 cand = T64 | (1ull << bit);
    unsigned c = 0;
#pragma unroll
    for (int q = 0; q < 9; ++q) c += (q < nk && k[q] >= cand) ? 1u : 0u;
#pragma unroll
    for (int s = 32; s > 0; s >>= 1) c += __shfl_down(c, s);
    if ((t & 63) == 0) atomicAdd(&cnt[bit], c);
    __syncthreads();
    if (cnt[bit] >= 64) T64 = cand;
  }

#pragma unroll
  for (int q = 0; q < 9; ++q) {
    if (q < nk && k[q] >= T64) {
      unsigned p = atomicAdd(&nsel, 1u);
      if (p < 64) selbuf[p] = k[q];
    }
  }
  __syncthreads();

  if (t < 64) {
    u64 key = selbuf[t];
#pragma unroll
    for (int kk = 2; kk <= 64; kk <<= 1) {
#pragma unroll
      for (int j = kk >> 1; j > 0; j >>= 1) {
        u64 other = __shfl_xor(key, j);
        const bool dirDesc = ((t & kk) == 0);
        const bool upper = ((t & j) != 0);
        u64 mx = umax64(key, other);
        u64 mn = (key < other) ? key : other;
        key = (dirDesc ^ upper) ? mx : mn;
      }
    }
    const unsigned ui = (unsigned)(key >> 32);
    const float v = __uint_as_float((ui & 0x80000000u) ? (ui ^ 0x80000000u) : ~ui);
    const int idx = (int)(0xFFFFFFFFu - (unsigned)(key & 0xFFFFFFFFull));
    topv[(size_t)row * KSEL + t] = v;
    topi[(size_t)row * KSEL + t] = idx;
  }
}

// ---------------- K2e: exps from final top-10 ----------------
__global__ __launch_bounds__(256) void k_exps(const float* __restrict__ topv, float* __restrict__ exps) {
  const int r = blockIdx.x * 256 + threadIdx.x;
  float s = 0.f;
#pragma unroll
  for (int q = 0; q < 10; ++q) s += topv[(size_t)r * KSEL + q];
  exps[r] = expf(s / 40.0f);
}

// ---------------- K2: full-row top-64 (fallback path) ----------------
__global__ __launch_bounds__(256) void k_topk(const float* __restrict__ simc,
                                              float* __restrict__ topv, int* __restrict__ topi,
                                              float* __restrict__ exps, int row0) {
  __shared__ float vals[NROWS];
  __shared__ u64 wmax[4];
  __shared__ float outv[KSEL];
  __shared__ int outi[KSEL];
  const int row = row0 + blockIdx.x;
  const int t = threadIdx.x;
  const float* src = simc + (size_t)blockIdx.x * NROWS;
  for (int i = t; i < NROWS; i += 256) vals[i] = src[i];
  __syncthreads();

  u64 lk = 0;
#pragma unroll
  for (int m = 0; m < 32; ++m) {
    int i = t + 256 * m;
    lk = umax64(lk, mkkey_vi(vals[i], i));
  }

  const int lane = t & 63, wv = t >> 6;
  for (int it = 0; it < KSEL; ++it) {
    u64 wk = lk;
#pragma unroll
    for (int s = 32; s > 0; s >>= 1) {
      u64 o = __shfl_xor(wk, s);
      wk = umax64(wk, o);
    }
    if (lane == 0) wmax[wv] = wk;
    __syncthreads();
    u64 g = umax64(umax64(wmax[0], wmax[1]), umax64(wmax[2], wmax[3]));
    const unsigned ui = (unsigned)(g >> 32);
    const float v = __uint_as_float((ui & 0x80000000u) ? (ui ^ 0x80000000u) : ~ui);
    const int idx = (int)(0xFFFFFFFFu - (unsigned)(g & 0xFFFFFFFFull));
    if (t == 0) { outv[it] = v; outi[it] = idx; }
    if (t == (idx & 255)) {
      vals[idx] = -INFINITY;
      u64 nl = 0;
#pragma unroll
      for (int m = 0; m < 32; ++m) {
        int i = t + 256 * m;
        nl = umax64(nl, mkkey_vi(vals[i], i));
      }
      lk = nl;
    }
    __syncthreads();
  }
  if (t < KSEL) {
    topv[(size_t)row * KSEL + t] = outv[t];
    topi[(size_t)row * KSEL + t] = outi[t];
  }
  if (t == 0) {
    float s = 0.f;
#pragma unroll
    for (int q = 0; q < 10; ++q) s += outv[q];
    exps[row] = expf(s / 40.0f);
  }
}

// ---------------- K3: adjacency build + row softmax ----------------
__global__ __launch_bounds__(256) void k_adj(const int* __restrict__ indexes,
                                             const float* __restrict__ topv, const int* __restrict__ topi,
                                             const float* __restrict__ exps, float* __restrict__ adj) {
  __shared__ int nbr[64];
  __shared__ int neigh[64][10];
  __shared__ float tv[64][10];
  __shared__ float adjL[64][64];
  const int b = blockIdx.x;
  const int t = threadIdx.x;
  const int idx = indexes[b];
  if (t < 64) nbr[t] = topi[(size_t)idx * KSEL + t];
  __syncthreads();
  for (int p = t; p < 640; p += 256) {
    const int r = p / 10, q = p - r * 10;
    const int m = nbr[r];
    const int c = topi[(size_t)m * KSEL + q];
    neigh[r][q] = c;
    tv[r][q] = topv[(size_t)m * KSEL + q] * exps[c];
  }
  __syncthreads();
  for (int p = t; p < 4096; p += 256) {
    const int i = p >> 6, j = p & 63;
    float s = 0.f;
#pragma unroll
    for (int q = 0; q < 10; ++q) {
      const int c = neigh[i][q];
      float add = 0.f;
      for (int s2 = 0; s2 < 10; ++s2) {
        if (neigh[j][s2] == c) { add = (tv[j][s2] > 0.f) ? tv[i][q] : 0.f; break; }
      }
      s += add;
    }
    adjL[i][j] = s;
  }
  __syncthreads();
  const int wv = t >> 6, lane = t & 63;
  for (int i = wv * 16; i < wv * 16 + 16; ++i) {
    float v = adjL[i][lane];
    float mx = v;
#pragma unroll
    for (int s = 32; s > 0; s >>= 1) mx = fmaxf(mx, __shfl_xor(mx, s));
    float e = expf(v - mx);
    float sum = e;
#pragma unroll
    for (int s = 32; s > 0; s >>= 1) sum += __shfl_xor(sum, s);
    adj[((size_t)b * 64 + i) * 64 + lane] = e / sum;
  }
}

// ---------------- K4: xs splits ----------------
__global__ __launch_bounds__(256) void k_xs_split(const int* __restrict__ indexes, const int* __restrict__ topi,
                                                  const float* __restrict__ F,
                                                  ushort* __restrict__ XH, ushort* __restrict__ XL) {
  const int b = blockIdx.y, r = blockIdx.x;
  const int t = threadIdx.x;
  const int idx = indexes[b];
  const int m  = topi[(size_t)idx * KSEL + r];
  const int m0 = topi[(size_t)idx * KSEL + 0];
  const float4* pa = (const float4*)(F + (size_t)m * DFEAT);
  const float4* pb = (const float4*)(F + (size_t)m0 * DFEAT);
  const size_t rowoff = ((size_t)b * 64 + r) * DFEAT;
#pragma unroll
  for (int it = 0; it < 2; ++it) {
    const int i = t + it * 256;
    float4 a = pa[i], c = pb[i];
    float d[4] = {a.x - c.x, a.y - c.y, a.z - c.z, a.w - c.w};
    ushort h[4], l[4];
#pragma unroll
    for (int q = 0; q < 4; ++q) split2(d[q], h[q], l[q]);
    ushort4 vh = {h[0], h[1], h[2], h[3]};
    ushort4 vl = {l[0], l[1], l[2], l[3]};
    *(ushort4*)(XH + rowoff + i * 4) = vh;
    *(ushort4*)(XL + rowoff + i * 4) = vl;
  }
}

// ---------------- K5: weight pre-split, transposed + combined ----------------
__global__ __launch_bounds__(256) void k_wsplitT(const float* __restrict__ W,
                                                 ushort* __restrict__ WTH, ushort* __restrict__ WTL,
                                                 int K, int F) {
  __shared__ float tile[32][33];
  const int k0 = blockIdx.x * 32;
  const int n0 = blockIdx.y * 32;
  const int t = threadIdx.x;
  {
    const int r = t >> 3, cq = t & 7;
    const int srcRow = (n0 < F) ? (k0 + r) : (K + k0 + r);
    const int srcCol = (n0 < F) ? n0 : (n0 - F);
    float4 v = *(const float4*)(W + (size_t)srcRow * F + srcCol + cq * 4);
    tile[r][cq * 4 + 0] = v.x; tile[r][cq * 4 + 1] = v.y;
    tile[r][cq * 4 + 2] = v.z; tile[r][cq * 4 + 3] = v.w;
  }
  __syncthreads();
  {
    const int nl = t >> 3, kq = t & 7;
    ushort h[4], l[4];
#pragma unroll
    for (int i = 0; i < 4; ++i) split2(tile[kq * 4 + i][nl], h[i], l[i]);
    ushort4 vh = {h[0], h[1], h[2], h[3]};
    ushort4 vl = {l[0], l[1], l[2], l[3]};
    *(ushort4*)(WTH + (size_t)(n0 + nl) * K + k0 + kq * 4) = vh;
    *(ushort4*)(WTL + (size_t)(n0 + nl) * K + k0 + kq * 4) = vl;
  }
}

// ---------------- K6: layer epilogue ----------------
__global__ __launch_bounds__(256) void k_postlayer(const float* __restrict__ C, const float* __restrict__ adj,
                                                   const float* __restrict__ bias,
                                                   ushort* __restrict__ HH, ushort* __restrict__ HL, int F) {
  __shared__ float adjL[64 * 65];
  __shared__ float QL[64 * 66];
  const int f0 = blockIdx.x * 64;
  const int b = blockIdx.y;
  const int t = threadIdx.x;
  const int fc = t & 63, rg = t >> 6;
  const int twoF = 2 * F;
  for (int i = t; i < 4096; i += 256) {
    const int r = i >> 6, j = i & 63;
    adjL[r * 65 + j] = adj[(size_t)b * 4096 + i];
    QL[r * 66 + j] = C[(size_t)(b * 64 + r) * twoF + F + f0 + j];
  }
  __syncthreads();
  const float bv = bias[f0 + fc];
  for (int rr = 0; rr < 16; ++rr) {
    const int r = rg * 16 + rr;
    float s = 0.f;
#pragma unroll 8
    for (int j0 = 0; j0 < 64; ++j0) {
      const int j = (j0 + fc) & 63;
      s += adjL[r * 65 + j] * QL[j * 66 + fc];
    }
    const int row = b * 64 + r;
    float h = C[(size_t)row * twoF + f0 + fc] + s + bv;
    h = fmaxf(h, 0.f);
    ushort hh, hl;
    split2(h, hh, hl);
    HH[(size_t)row * F + f0 + fc] = hh;
    HL[(size_t)row * F + f0 + fc] = hl;
  }
}

// ---------------- K7: classifier epilogue ----------------
__global__ __launch_bounds__(256) void k_postcls(const float* __restrict__ C, const float* __restrict__ bias,
                                                 const float* __restrict__ pre, float* __restrict__ HC) {
  const size_t i0 = ((size_t)blockIdx.x * 256 + threadIdx.x) * 4;
  const int col = (int)(i0 & 255);
  float4 c = *(const float4*)(C + i0);
  float o[4] = {c.x, c.y, c.z, c.w};
#pragma unroll
  for (int i = 0; i < 4; ++i) {
    float h = o[i] + bias[col + i];
    o[i] = (h > 0.f) ? h : pre[col + i] * h;
  }
  *(float4*)(HC + i0) = make_float4(o[0], o[1], o[2], o[3]);
}

// ---------------- K8: pred = HC @ Wc2 + bc2 ----------------
__global__ __launch_bounds__(256) void k_final(const float* __restrict__ Hc, const float* __restrict__ Wc2,
                                               const float* __restrict__ bc2, float* __restrict__ outp) {
  __shared__ float w[512];
  __shared__ float red[512];
  const int t = threadIdx.x;
  for (int i = t; i < 512; i += 256) w[i] = Wc2[i];
  __syncthreads();
  const int m = blockIdx.x * 64 + (t >> 2);
  const int p = t & 3;
  const float* h = Hc + (size_t)m * 256;
  float s0 = 0.f, s1 = 0.f;
  for (int k = p * 64; k < p * 64 + 64; ++k) {
    float hv = h[k];
    s0 += hv * w[k * 2];
    s1 += hv * w[k * 2 + 1];
  }
  red[t * 2] = s0; red[t * 2 + 1] = s1;
  __syncthreads();
  if (p == 0) {
    for (int q = 1; q < 4; ++q) { s0 += red[(t + q) * 2]; s1 += red[(t + q) * 2 + 1]; }
    outp[m * 2 + 0] = s0 + bc2[0];
    outp[m * 2 + 1] = s1 + bc2[1];
  }
}

extern "C" void kernel_launch(void* const* d_in, const int* in_sizes, int n_in,
                              void* d_out, int out_size, void* d_ws, size_t ws_size,
                              hipStream_t stream) {
  const int*   indexes = (const int*)d_in[0];
  const float* F   = (const float*)d_in[1];
  const float* W1  = (const float*)d_in[4];
  const float* b1  = (const float*)d_in[5];
  const float* W2  = (const float*)d_in[6];
  const float* b2  = (const float*)d_in[7];
  const float* W3  = (const float*)d_in[8];
  const float* b3  = (const float*)d_in[9];
  const float* W4  = (const float*)d_in[10];
  const float* b4  = (const float*)d_in[11];
  const float* Wc1 = (const float*)d_in[12];
  const float* bc1 = (const float*)d_in[13];
  const float* pre = (const float*)d_in[14];
  const float* Wc2 = (const float*)d_in[15];
  const float* bc2 = (const float*)d_in[16];
  float* out = (float*)d_out;

  size_t off = 0;
  auto take = [&](size_t bytes) -> char* {
    char* q = (char*)d_ws + off;
    off += (bytes + 255) & ~(size_t)255;
    return q;
  };
  float* TOPV = (float*)take((size_t)NROWS * KSEL * 4);
  int*   TOPI = (int*)  take((size_t)NROWS * KSEL * 4);
  float* EXPS = (float*)take((size_t)NROWS * 4);
  float* ADJ  = (float*)take((size_t)64 * 64 * 64 * 4);
  char*  big  = (char*)d_ws + off;
  const size_t big_bytes = (ws_size > off) ? (ws_size - off) : 0;

  const size_t Mi = 1024 * 1024;
  const size_t Ki = 1024;
  const size_t splitBytes = (size_t)NROWS * DFEAT * 2;

  if (big_bytes >= 160 * Mi) {
    ushort* FH = (ushort*)big;
    ushort* FM = (ushort*)(big + splitBytes);
    ushort* FL = (ushort*)(big + 2 * splitBytes);
    float* TILE0  = (float*)(big + 96 * Mi);
    float* TILE0T = (float*)(big + 112 * Mi);
    float* TILE1  = (float*)(big + 128 * Mi);
    float* TILE1T = (float*)(big + 144 * Mi);
    k_split<<<NROWS * DFEAT / 1024, 256, 0, stream>>>(F, FH, FM, FL);
    k_init_topk<<<NROWS * KSEL / 256, 256, 0, stream>>>(TOPV, TOPI);
    const int pairs[10][2] = {{0,0},{0,1},{0,2},{0,3},{1,1},{1,2},{1,3},{2,2},{2,3},{3,3}};
    for (int b = 0; b < 5; ++b) {
      const int ia = pairs[2*b][0],   ja = pairs[2*b][1];
      const int ib = pairs[2*b+1][0], jb = pairs[2*b+1][1];
      k_simgemm_pair<<<dim3(16, 16, 2), 256, 0, stream>>>(
          FH, FM, FL,
          TILE0, (ia != ja) ? TILE0T : nullptr, ia, ja,
          TILE1, (ib != jb) ? TILE1T : nullptr, ib, jb);
      k_topk_update<<<CHK, 256, 0, stream>>>(TILE0, ia * CHK, ja * CHK, TOPV, TOPI);
      if (ia != ja) k_topk_update<<<CHK, 256, 0, stream>>>(TILE0T, ja * CHK, ia * CHK, TOPV, TOPI);
      k_topk_update<<<CHK, 256, 0, stream>>>(TILE1, ib * CHK, jb * CHK, TOPV, TOPI);
      if (ib != jb) k_topk_update<<<CHK, 256, 0, stream>>>(TILE1T, jb * CHK, ib * CHK, TOPV, TOPI);
    }
    k_exps<<<NROWS / 256, 256, 0, stream>>>(TOPV, EXPS);
  } else {
    int fchunk = 0;
    for (int c = 2048; c >= 512; c >>= 1) {
      if (3 * splitBytes + (size_t)c * NROWS * 4 <= big_bytes) { fchunk = c; break; }
    }
    if (fchunk == 0) {
      hipMemsetAsync(d_out, 0, (size_t)out_size * 4, stream);
      return;
    }
    ushort* FH = (ushort*)big;
    ushort* FM = (ushort*)(big + splitBytes);
    ushort* FL = (ushort*)(big + 2 * splitBytes);
    float* SIMC = (float*)(big + 3 * splitBytes);
    k_split<<<NROWS * DFEAT / 1024, 256, 0, stream>>>(F, FH, FM, FL);
    for (int r0 = 0; r0 < NROWS; r0 += fchunk) {
      k_simgemm_mfma<<<dim3(64, fchunk / 128), 256, 0, stream>>>(FH, FM, FL, SIMC, r0);
      k_topk<<<fchunk, 256, 0, stream>>>(SIMC, TOPV, TOPI, EXPS, r0);
    }
  }
  k_adj<<<64, 256, 0, stream>>>(indexes, TOPV, TOPI, EXPS, ADJ);

  ushort* XH   = (ushort*)(big);
  ushort* XL   = (ushort*)(big + 16 * Mi);
  ushort* WT1H = (ushort*)(big + 32 * Mi);
  ushort* WT1L = (ushort*)(big + 40 * Mi);
  ushort* WT2H = (ushort*)(big + 48 * Mi);
  ushort* WT2L = (ushort*)(big + 50 * Mi);
  ushort* WT3H = (ushort*)(big + 52 * Mi);
  ushort* WT3L = (ushort*)(big + 52 * Mi + 512 * Ki);
  ushort* WT4H = (ushort*)(big + 53 * Mi);
  ushort* WT4L = (ushort*)(big + 53 * Mi + 256 * Ki);
  ushort* WTcH = (ushort*)(big + 53 * Mi + 512 * Ki);
  ushort* WTcL = (ushort*)(big + 53 * Mi + 640 * Ki);
  float*  CBUF = (float*)(big + 54 * Mi);
  float*  HC   = (float*)(big + 86 * Mi);
  ushort* H1H  = (ushort*)(big + 32 * Mi);
  ushort* H1L  = (ushort*)(big + 40 * Mi);
  ushort* H2H  = (ushort*)(big);
  ushort* H2L  = (ushort*)(big + 4 * Mi);
  ushort* H3H  = (ushort*)(big + 8 * Mi);
  ushort* H3L  = (ushort*)(big + 10 * Mi);
  ushort* H4H  = (ushort*)(big + 12 * Mi);
  ushort* H4L  = (ushort*)(big + 14 * Mi);

  k_wsplitT<<<dim3(2048 / 32, 2048 / 32), 256, 0, stream>>>(W1, WT1H, WT1L, 2048, 1024);
  k_wsplitT<<<dim3(1024 / 32, 1024 / 32), 256, 0, stream>>>(W2, WT2H, WT2L, 1024, 512);
  k_wsplitT<<<dim3(512 / 32, 512 / 32), 256, 0, stream>>>(W3, WT3H, WT3L, 512, 256);
  k_wsplitT<<<dim3(256 / 32, 512 / 32), 256, 0, stream>>>(W4, WT4H, WT4L, 256, 256);
  k_wsplitT<<<dim3(256 / 32, 256 / 32), 256, 0, stream>>>(Wc1, WTcH, WTcL, 256, 256);

  k_xs_split<<<dim3(64, 64), 256, 0, stream>>>(indexes, TOPI, F, XH, XL);

  k_gemm3<<<dim3(16, 32), 256, 0, stream>>>(XH, XL, WT1H, WT1L, CBUF, 2048, 2048);
  k_postlayer<<<dim3(16, 64), 256, 0, stream>>>(CBUF, ADJ, b1, H1H, H1L, 1024);
  k_gemm3<<<dim3(8, 32), 256, 0, stream>>>(H1H, H1L, WT2H, WT2L, CBUF, 1024, 1024);
  k_postlayer<<<dim3(8, 64), 256, 0, stream>>>(CBUF, ADJ, b2, H2H, H2L, 512);
  k_gemm3<<<dim3(4, 32), 256, 0, stream>>>(H2H, H2L, WT3H, WT3L, CBUF, 512, 512);
  k_postlayer<<<dim3(4, 64), 256, 0, stream>>>(CBUF, ADJ, b3, H3H, H3L, 256);
  k_gemm3<<<dim3(4, 32), 256, 0, stream>>>(H3H, H3L, WT4H, WT4L, CBUF, 256, 512);
  k_postlayer<<<dim3(4, 64), 256, 0, stream>>>(CBUF, ADJ, b4, H4H, H4L, 256);
  k_gemm3<<<dim3(2, 32), 256, 0, stream>>>(H4H, H4L, WTcH, WTcL, CBUF, 256, 256);
  k_postcls<<<4096 * 256 / 1024, 256, 0, stream>>>(CBUF, bc1, pre, HC);

  k_final<<<64, 256, 0, stream>>>(HC, Wc2, bc2, out);
}

// Round 9
// 1649.943 us; speedup vs baseline: 2.1318x; 1.3381x over previous
//
#include <hip/hip_runtime.h>
#include <hip/hip_bf16.h>
#include <math.h>

#define NROWS 8192
#define DFEAT 2048
#define KSEL  64
#define CHK   2048   // symmetric pair chunk

typedef unsigned long long u64;
typedef __attribute__((ext_vector_type(8))) short bf16x8;
typedef __attribute__((ext_vector_type(4))) float f32x4;

__device__ __forceinline__ u64 umax64(u64 a, u64 b) { return a > b ? a : b; }

__device__ __forceinline__ void split2(float v, ushort& h, ushort& l) {
  __hip_bfloat16 bh = __float2bfloat16(v);
  float r = v - __bfloat162float(bh);
  __hip_bfloat16 bl = __float2bfloat16(r);
  h = *(ushort*)&bh; l = *(ushort*)&bl;
}

__device__ __forceinline__ u64 mkkey_vi(float v, int i) {
  unsigned u = __float_as_uint(v);
  u = ((int)u < 0) ? ~u : (u | 0x80000000u);
  return ((u64)u << 32) | (u64)(0xFFFFFFFFu - (unsigned)i);
}

// ---------------- K0: 3-way bf16 split of F (exact to 2^-27) ----------------
__global__ __launch_bounds__(256) void k_split(const float* __restrict__ F, ushort* __restrict__ H,
                                               ushort* __restrict__ M, ushort* __restrict__ L) {
  const size_t i0 = ((size_t)blockIdx.x * 256 + threadIdx.x) * 4;
  float4 x = *(const float4*)(F + i0);
  float xs[4] = {x.x, x.y, x.z, x.w};
  ushort h[4], m[4], l[4];
#pragma unroll
  for (int c = 0; c < 4; ++c) {
    float v = xs[c];
    __hip_bfloat16 bh = __float2bfloat16(v);
    float r1 = v - __bfloat162float(bh);
    __hip_bfloat16 bm = __float2bfloat16(r1);
    float r2 = r1 - __bfloat162float(bm);
    __hip_bfloat16 bl = __float2bfloat16(r2);
    h[c] = *(ushort*)&bh; m[c] = *(ushort*)&bm; l[c] = *(ushort*)&bl;
  }
  ushort4 vh = {h[0], h[1], h[2], h[3]};
  ushort4 vm = {m[0], m[1], m[2], m[3]};
  ushort4 vl = {l[0], l[1], l[2], l[3]};
  *(ushort4*)(H + i0) = vh;
  *(ushort4*)(M + i0) = vm;
  *(ushort4*)(L + i0) = vl;
}

// ---------------- K1p: symmetric pair tile GEMM (bf16x6), 2 pairs per launch ----------------
// Swizzled LDS (R8). Diagonal pairs (diag=1): TILT==TILE, blocks bm>bj exit,
// bm<bj mirror-write the transpose into the same tile (bitwise-identical by MFMA symmetry).
__global__ __launch_bounds__(256) void k_simgemm_pair(
    const ushort* __restrict__ FH, const ushort* __restrict__ FM, const ushort* __restrict__ FL,
    float* __restrict__ T0, float* __restrict__ T0T, int i0, int j0, int d0,
    float* __restrict__ T1, float* __restrict__ T1T, int i1, int j1, int d1) {
  __shared__ ushort lds[6 * 4096];
  const int z = blockIdx.z;
  float* TILE = z ? T1 : T0;
  float* TILT = z ? T1T : T0T;
  const int ci = z ? i1 : i0;
  const int cj = z ? j1 : j0;
  const int diag = z ? d1 : d0;
  const int bj = blockIdx.x;
  const int bm = blockIdx.y;
  if (diag && bm > bj) return;   // lower-triangle blocks of diagonal tiles: mirrored instead
  const int t = threadIdx.x;
  const int w = t >> 6, l = t & 63;
  const int arow0 = ci * CHK + bm * 128;
  const int brow0 = cj * CHK + bj * 128;
  const int segr = l >> 2;
  const int segq_s = (l & 3) ^ ((l >> 3) & 3);   // swizzled k-slot for staging
  const int fl15 = l & 15, fq = l >> 4;
  const int kswz = (fq ^ ((fl15 >> 1) & 3)) * 8; // swizzled k-slot for reads
  const int wr = w >> 1, wc = w & 1;
  const int mb = wr * 64, nb = wc * 64;

  f32x4 acc[4][4];
#pragma unroll
  for (int i = 0; i < 4; ++i)
#pragma unroll
    for (int j = 0; j < 4; ++j) acc[i][j] = (f32x4){0.f, 0.f, 0.f, 0.f};

  for (int k0 = 0; k0 < DFEAT; k0 += 32) {
    __syncthreads();
#pragma unroll
    for (int c = 0; c < 12; ++c) {
      const int cc = w * 12 + c;
      const int tt = cc >> 3;
      const int p = cc & 7;
      const int rowbase = (tt < 3) ? arow0 : brow0;
      const int sp = (tt < 3) ? tt : (tt - 3);
      const ushort* sel = (sp == 0) ? FH : ((sp == 1) ? FM : FL);
      const ushort* g = sel + (size_t)(rowbase + p * 16 + segr) * DFEAT + (k0 + segq_s * 8);
      __builtin_amdgcn_global_load_lds((const __attribute__((address_space(1))) unsigned int*)g,
                                       (__attribute__((address_space(3))) unsigned int*)&lds[tt * 4096 + p * 512],
                                       16, 0, 0);
    }
    __syncthreads();

    bf16x8 af[3][4];
    bf16x8 bg[3][4];
#pragma unroll
    for (int i = 0; i < 3; ++i)
#pragma unroll
      for (int fm = 0; fm < 4; ++fm)
        af[i][fm] = *(const bf16x8*)&lds[i * 4096 + (mb + fm * 16 + fl15) * 32 + kswz];
#pragma unroll
    for (int j = 0; j < 3; ++j)
#pragma unroll
      for (int fn = 0; fn < 4; ++fn)
        bg[j][fn] = *(const bf16x8*)&lds[(3 + j) * 4096 + (nb + fn * 16 + fl15) * 32 + kswz];

#pragma unroll
    for (int fm = 0; fm < 4; ++fm)
#pragma unroll
      for (int fn = 0; fn < 4; ++fn) {
        f32x4 a = acc[fm][fn];
        a = __builtin_amdgcn_mfma_f32_16x16x32_bf16(af[0][fm], bg[0][fn], a, 0, 0, 0);
        a = __builtin_amdgcn_mfma_f32_16x16x32_bf16(af[1][fm], bg[0][fn], a, 0, 0, 0);
        a = __builtin_amdgcn_mfma_f32_16x16x32_bf16(af[0][fm], bg[1][fn], a, 0, 0, 0);
        a = __builtin_amdgcn_mfma_f32_16x16x32_bf16(af[2][fm], bg[0][fn], a, 0, 0, 0);
        a = __builtin_amdgcn_mfma_f32_16x16x32_bf16(af[0][fm], bg[2][fn], a, 0, 0, 0);
        a = __builtin_amdgcn_mfma_f32_16x16x32_bf16(af[1][fm], bg[1][fn], a, 0, 0, 0);
        acc[fm][fn] = a;
      }
  }

  const bool doT = (TILT != nullptr) && !(diag && bm == bj);
#pragma unroll
  for (int fm = 0; fm < 4; ++fm) {
    const int lm = bm * 128 + mb + fm * 16 + fq * 4;
#pragma unroll
    for (int fn = 0; fn < 4; ++fn) {
      const int col = bj * 128 + nb + fn * 16 + fl15;
#pragma unroll
      for (int r = 0; r < 4; ++r)
        TILE[(size_t)(lm + r) * CHK + col] = acc[fm][fn][r];
      if (doT) {
        float4 v = make_float4(acc[fm][fn][0], acc[fm][fn][1], acc[fm][fn][2], acc[fm][fn][3]);
        *(float4*)(TILT + (size_t)col * CHK + lm) = v;
      }
    }
  }
}

// ---------------- K1: chunked row-panel sim (fallback, proven, unswizzled) ----------------
__global__ __launch_bounds__(256) void k_simgemm_mfma(
    const ushort* __restrict__ FH, const ushort* __restrict__ FM, const ushort* __restrict__ FL,
    float* __restrict__ C, int row0) {
  __shared__ ushort lds[6 * 4096];
  const int bj = blockIdx.x;
  const int bm = blockIdx.y;
  const int t = threadIdx.x;
  const int w = t >> 6, l = t & 63;
  const int arow0 = row0 + bm * 128;
  const int brow0 = bj * 128;
  const int segr = l >> 2;
  const int segq = l & 3;
  const int fl15 = l & 15, fq = l >> 4;
  const int wr = w >> 1, wc = w & 1;
  const int mb = wr * 64, nb = wc * 64;

  f32x4 acc[4][4];
#pragma unroll
  for (int i = 0; i < 4; ++i)
#pragma unroll
    for (int j = 0; j < 4; ++j) acc[i][j] = (f32x4){0.f, 0.f, 0.f, 0.f};

  for (int k0 = 0; k0 < DFEAT; k0 += 32) {
    __syncthreads();
#pragma unroll
    for (int c = 0; c < 12; ++c) {
      const int cc = w * 12 + c;
      const int tt = cc >> 3;
      const int p = cc & 7;
      const int rowbase = (tt < 3) ? arow0 : brow0;
      const int sp = (tt < 3) ? tt : (tt - 3);
      const ushort* sel = (sp == 0) ? FH : ((sp == 1) ? FM : FL);
      const ushort* g = sel + (size_t)(rowbase + p * 16 + segr) * DFEAT + (k0 + segq * 8);
      __builtin_amdgcn_global_load_lds((const __attribute__((address_space(1))) unsigned int*)g,
                                       (__attribute__((address_space(3))) unsigned int*)&lds[tt * 4096 + p * 512],
                                       16, 0, 0);
    }
    __syncthreads();

    bf16x8 af[3][4];
    bf16x8 bg[3][4];
    const int kcol = fq * 8;
#pragma unroll
    for (int i = 0; i < 3; ++i)
#pragma unroll
      for (int fm = 0; fm < 4; ++fm)
        af[i][fm] = *(const bf16x8*)&lds[i * 4096 + (mb + fm * 16 + fl15) * 32 + kcol];
#pragma unroll
    for (int j = 0; j < 3; ++j)
#pragma unroll
      for (int fn = 0; fn < 4; ++fn)
        bg[j][fn] = *(const bf16x8*)&lds[(3 + j) * 4096 + (nb + fn * 16 + fl15) * 32 + kcol];

#pragma unroll
    for (int fm = 0; fm < 4; ++fm)
#pragma unroll
      for (int fn = 0; fn < 4; ++fn) {
        f32x4 a = acc[fm][fn];
        a = __builtin_amdgcn_mfma_f32_16x16x32_bf16(af[0][fm], bg[0][fn], a, 0, 0, 0);
        a = __builtin_amdgcn_mfma_f32_16x16x32_bf16(af[1][fm], bg[0][fn], a, 0, 0, 0);
        a = __builtin_amdgcn_mfma_f32_16x16x32_bf16(af[0][fm], bg[1][fn], a, 0, 0, 0);
        a = __builtin_amdgcn_mfma_f32_16x16x32_bf16(af[2][fm], bg[0][fn], a, 0, 0, 0);
        a = __builtin_amdgcn_mfma_f32_16x16x32_bf16(af[0][fm], bg[2][fn], a, 0, 0, 0);
        a = __builtin_amdgcn_mfma_f32_16x16x32_bf16(af[1][fm], bg[1][fn], a, 0, 0, 0);
        acc[fm][fn] = a;
      }
  }

#pragma unroll
  for (int fm = 0; fm < 4; ++fm) {
    const int lm = bm * 128 + mb + fm * 16 + fq * 4;
#pragma unroll
    for (int fn = 0; fn < 4; ++fn) {
      const int col = bj * 128 + nb + fn * 16 + fl15;
#pragma unroll
      for (int r = 0; r < 4; ++r)
        C[(size_t)(lm + r) * NROWS + col] = acc[fm][fn][r];
    }
  }
}

// ---------------- K1b: generic bf16x3 MFMA GEMM: C = A . B^T (swizzled LDS) ----------------
__global__ __launch_bounds__(256) void k_gemm3(const ushort* __restrict__ AH, const ushort* __restrict__ AL,
                                               const ushort* __restrict__ BH, const ushort* __restrict__ BL,
                                               float* __restrict__ C, int K, int N) {
  __shared__ ushort lds[4 * 4096];
  const int bj = blockIdx.x, bm = blockIdx.y;
  const int t = threadIdx.x;
  const int w = t >> 6, l = t & 63;
  const int segr = l >> 2;
  const int segq_s = (l & 3) ^ ((l >> 3) & 3);
  const int fl15 = l & 15, fq = l >> 4;
  const int kswz = (fq ^ ((fl15 >> 1) & 3)) * 8;
  const int wr = w >> 1, wc = w & 1;
  const int mb = wr * 64, nb = wc * 64;

  f32x4 acc[4][4];
#pragma unroll
  for (int i = 0; i < 4; ++i)
#pragma unroll
    for (int j = 0; j < 4; ++j) acc[i][j] = (f32x4){0.f, 0.f, 0.f, 0.f};

  for (int k0 = 0; k0 < K; k0 += 32) {
    __syncthreads();
#pragma unroll
    for (int c = 0; c < 8; ++c) {
      const int s = w * 8 + c;
      const int tt = s >> 3;
      const int p = s & 7;
      const int rowbase = (tt < 2) ? (bm * 128) : (bj * 128);
      const ushort* sel = (tt == 0) ? AH : ((tt == 1) ? AL : ((tt == 2) ? BH : BL));
      const ushort* g = sel + (size_t)(rowbase + p * 16 + segr) * K + (k0 + segq_s * 8);
      __builtin_amdgcn_global_load_lds((const __attribute__((address_space(1))) unsigned int*)g,
                                       (__attribute__((address_space(3))) unsigned int*)&lds[s * 512],
                                       16, 0, 0);
    }
    __syncthreads();

    bf16x8 af[2][4];
    bf16x8 bg[2][4];
#pragma unroll
    for (int i = 0; i < 2; ++i)
#pragma unroll
      for (int fm = 0; fm < 4; ++fm)
        af[i][fm] = *(const bf16x8*)&lds[i * 4096 + (mb + fm * 16 + fl15) * 32 + kswz];
#pragma unroll
    for (int j = 0; j < 2; ++j)
#pragma unroll
      for (int fn = 0; fn < 4; ++fn)
        bg[j][fn] = *(const bf16x8*)&lds[(2 + j) * 4096 + (nb + fn * 16 + fl15) * 32 + kswz];

#pragma unroll
    for (int fm = 0; fm < 4; ++fm)
#pragma unroll
      for (int fn = 0; fn < 4; ++fn) {
        f32x4 a = acc[fm][fn];
        a = __builtin_amdgcn_mfma_f32_16x16x32_bf16(af[0][fm], bg[0][fn], a, 0, 0, 0);
        a = __builtin_amdgcn_mfma_f32_16x16x32_bf16(af[0][fm], bg[1][fn], a, 0, 0, 0);
        a = __builtin_amdgcn_mfma_f32_16x16x32_bf16(af[1][fm], bg[0][fn], a, 0, 0, 0);
        acc[fm][fn] = a;
      }
  }

#pragma unroll
  for (int fm = 0; fm < 4; ++fm) {
    const int row = bm * 128 + mb + fm * 16 + fq * 4;
#pragma unroll
    for (int fn = 0; fn < 4; ++fn) {
      const int col = bj * 128 + nb + fn * 16 + fl15;
#pragma unroll
      for (int r = 0; r < 4; ++r)
        C[(size_t)(row + r) * N + col] = acc[fm][fn][r];
    }
  }
}

// ---------------- K2i: init running top-k ----------------
__global__ __launch_bounds__(256) void k_init_topk(float* __restrict__ topv, int* __restrict__ topi) {
  const int i = blockIdx.x * 256 + threadIdx.x;
  topv[i] = -INFINITY;
  topi[i] = 0;
}

// ---------------- K2u: merge-update running top-64 (early-exit binary select + bitonic sort) ----------------
__global__ __launch_bounds__(256) void k_topk_update(const float* __restrict__ T, int rowbase, int colbase,
                                                     float* __restrict__ topv, int* __restrict__ topi) {
  __shared__ unsigned cnt[64];
  __shared__ unsigned nsel;
  __shared__ u64 selbuf[64];
  const int t = threadIdx.x;
  const int row = rowbase + blockIdx.x;
  const float* src = T + (size_t)blockIdx.x * CHK;

  if (t < 64) cnt[t] = 0;
  if (t == 0) nsel = 0;

  u64 k[9];
  int nk = 8;
#pragma unroll
  for (int q = 0; q < 8; ++q) {
    float v = src[t + 256 * q];
    k[q] = mkkey_vi(v, colbase + t + 256 * q);
  }
  k[8] = 0;
  if (t < 64) {
    k[8] = mkkey_vi(topv[(size_t)row * KSEL + t], topi[(size_t)row * KSEL + t]);
    nk = 9;
  }
  __syncthreads();

  // bit-by-bit threshold build with early exit at exact count==64
  u64 T64 = 0;
  for (int bit = 63; bit >= 0; --bit) {
    const u64 cand = T64 | (1ull << bit);
    unsigned c = 0;
#pragma unroll
    for (int q = 0; q < 9; ++q) c += (q < nk && k[q] >= cand) ? 1u : 0u;
#pragma unroll
    for (int s = 32; s > 0; s >>= 1) c += __shfl_down(c, s);
    if ((t & 63) == 0) atomicAdd(&cnt[bit], c);
    __syncthreads();
    const unsigned cb = cnt[bit];
    if (cb >= 64) T64 = cand;
    if (cb == 64) break;   // threshold with exactly 64 keys >= it found (uniform)
  }

#pragma unroll
  for (int q = 0; q < 9; ++q) {
    if (q < nk && k[q] >= T64) {
      unsigned p = atomicAdd(&nsel, 1u);
      if (p < 64) selbuf[p] = k[q];
    }
  }
  __syncthreads();

  if (t < 64) {
    u64 key = selbuf[t];
#pragma unroll
    for (int kk = 2; kk <= 64; kk <<= 1) {
#pragma unroll
      for (int j = kk >> 1; j > 0; j >>= 1) {
        u64 other = __shfl_xor(key, j);
        const bool dirDesc = ((t & kk) == 0);
        const bool upper = ((t & j) != 0);
        u64 mx = umax64(key, other);
        u64 mn = (key < other) ? key : other;
        key = (dirDesc ^ upper) ? mx : mn;
      }
    }
    const unsigned ui = (unsigned)(key >> 32);
    const float v = __uint_as_float((ui & 0x80000000u) ? (ui ^ 0x80000000u) : ~ui);
    const int idx = (int)(0xFFFFFFFFu - (unsigned)(key & 0xFFFFFFFFull));
    topv[(size_t)row * KSEL + t] = v;
    topi[(size_t)row * KSEL + t] = idx;
  }
}

// ---------------- K2e: exps from final top-10 ----------------
__global__ __launch_bounds__(256) void k_exps(const float* __restrict__ topv, float* __restrict__ exps) {
  const int r = blockIdx.x * 256 + threadIdx.x;
  float s = 0.f;
#pragma unroll
  for (int q = 0; q < 10; ++q) s += topv[(size_t)r * KSEL + q];
  exps[r] = expf(s / 40.0f);
}

// ---------------- K2: full-row top-64 (fallback path) ----------------
__global__ __launch_bounds__(256) void k_topk(const float* __restrict__ simc,
                                              float* __restrict__ topv, int* __restrict__ topi,
                                              float* __restrict__ exps, int row0) {
  __shared__ float vals[NROWS];
  __shared__ u64 wmax[4];
  __shared__ float outv[KSEL];
  __shared__ int outi[KSEL];
  const int row = row0 + blockIdx.x;
  const int t = threadIdx.x;
  const float* src = simc + (size_t)blockIdx.x * NROWS;
  for (int i = t; i < NROWS; i += 256) vals[i] = src[i];
  __syncthreads();

  u64 lk = 0;
#pragma unroll
  for (int m = 0; m < 32; ++m) {
    int i = t + 256 * m;
    lk = umax64(lk, mkkey_vi(vals[i], i));
  }

  const int lane = t & 63, wv = t >> 6;
  for (int it = 0; it < KSEL; ++it) {
    u64 wk = lk;
#pragma unroll
    for (int s = 32; s > 0; s >>= 1) {
      u64 o = __shfl_xor(wk, s);
      wk = umax64(wk, o);
    }
    if (lane == 0) wmax[wv] = wk;
    __syncthreads();
    u64 g = umax64(umax64(wmax[0], wmax[1]), umax64(wmax[2], wmax[3]));
    const unsigned ui = (unsigned)(g >> 32);
    const float v = __uint_as_float((ui & 0x80000000u) ? (ui ^ 0x80000000u) : ~ui);
    const int idx = (int)(0xFFFFFFFFu - (unsigned)(g & 0xFFFFFFFFull));
    if (t == 0) { outv[it] = v; outi[it] = idx; }
    if (t == (idx & 255)) {
      vals[idx] = -INFINITY;
      u64 nl = 0;
#pragma unroll
      for (int m = 0; m < 32; ++m) {
        int i = t + 256 * m;
        nl = umax64(nl, mkkey_vi(vals[i], i));
      }
      lk = nl;
    }
    __syncthreads();
  }
  if (t < KSEL) {
    topv[(size_t)row * KSEL + t] = outv[t];
    topi[(size_t)row * KSEL + t] = outi[t];
  }
  if (t == 0) {
    float s = 0.f;
#pragma unroll
    for (int q = 0; q < 10; ++q) s += outv[q];
    exps[row] = expf(s / 40.0f);
  }
}

// ---------------- K3: adjacency build + row softmax ----------------
__global__ __launch_bounds__(256) void k_adj(const int* __restrict__ indexes,
                                             const float* __restrict__ topv, const int* __restrict__ topi,
                                             const float* __restrict__ exps, float* __restrict__ adj) {
  __shared__ int nbr[64];
  __shared__ int neigh[64][10];
  __shared__ float tv[64][10];
  __shared__ float adjL[64][64];
  const int b = blockIdx.x;
  const int t = threadIdx.x;
  const int idx = indexes[b];
  if (t < 64) nbr[t] = topi[(size_t)idx * KSEL + t];
  __syncthreads();
  for (int p = t; p < 640; p += 256) {
    const int r = p / 10, q = p - r * 10;
    const int m = nbr[r];
    const int c = topi[(size_t)m * KSEL + q];
    neigh[r][q] = c;
    tv[r][q] = topv[(size_t)m * KSEL + q] * exps[c];
  }
  __syncthreads();
  for (int p = t; p < 4096; p += 256) {
    const int i = p >> 6, j = p & 63;
    float s = 0.f;
#pragma unroll
    for (int q = 0; q < 10; ++q) {
      const int c = neigh[i][q];
      float add = 0.f;
      for (int s2 = 0; s2 < 10; ++s2) {
        if (neigh[j][s2] == c) { add = (tv[j][s2] > 0.f) ? tv[i][q] : 0.f; break; }
      }
      s += add;
    }
    adjL[i][j] = s;
  }
  __syncthreads();
  const int wv = t >> 6, lane = t & 63;
  for (int i = wv * 16; i < wv * 16 + 16; ++i) {
    float v = adjL[i][lane];
    float mx = v;
#pragma unroll
    for (int s = 32; s > 0; s >>= 1) mx = fmaxf(mx, __shfl_xor(mx, s));
    float e = expf(v - mx);
    float sum = e;
#pragma unroll
    for (int s = 32; s > 0; s >>= 1) sum += __shfl_xor(sum, s);
    adj[((size_t)b * 64 + i) * 64 + lane] = e / sum;
  }
}

// ---------------- K4: xs splits ----------------
__global__ __launch_bounds__(256) void k_xs_split(const int* __restrict__ indexes, const int* __restrict__ topi,
                                                  const float* __restrict__ F,
                                                  ushort* __restrict__ XH, ushort* __restrict__ XL) {
  const int b = blockIdx.y, r = blockIdx.x;
  const int t = threadIdx.x;
  const int idx = indexes[b];
  const int m  = topi[(size_t)idx * KSEL + r];
  const int m0 = topi[(size_t)idx * KSEL + 0];
  const float4* pa = (const float4*)(F + (size_t)m * DFEAT);
  const float4* pb = (const float4*)(F + (size_t)m0 * DFEAT);
  const size_t rowoff = ((size_t)b * 64 + r) * DFEAT;
#pragma unroll
  for (int it = 0; it < 2; ++it) {
    const int i = t + it * 256;
    float4 a = pa[i], c = pb[i];
    float d[4] = {a.x - c.x, a.y - c.y, a.z - c.z, a.w - c.w};
    ushort h[4], l[4];
#pragma unroll
    for (int q = 0; q < 4; ++q) split2(d[q], h[q], l[q]);
    ushort4 vh = {h[0], h[1], h[2], h[3]};
    ushort4 vl = {l[0], l[1], l[2], l[3]};
    *(ushort4*)(XH + rowoff + i * 4) = vh;
    *(ushort4*)(XL + rowoff + i * 4) = vl;
  }
}

// ---------------- K5: weight pre-split, transposed + combined ----------------
__global__ __launch_bounds__(256) void k_wsplitT(const float* __restrict__ W,
                                                 ushort* __restrict__ WTH, ushort* __restrict__ WTL,
                                                 int K, int F) {
  __shared__ float tile[32][33];
  const int k0 = blockIdx.x * 32;
  const int n0 = blockIdx.y * 32;
  const int t = threadIdx.x;
  {
    const int r = t >> 3, cq = t & 7;
    const int srcRow = (n0 < F) ? (k0 + r) : (K + k0 + r);
    const int srcCol = (n0 < F) ? n0 : (n0 - F);
    float4 v = *(const float4*)(W + (size_t)srcRow * F + srcCol + cq * 4);
    tile[r][cq * 4 + 0] = v.x; tile[r][cq * 4 + 1] = v.y;
    tile[r][cq * 4 + 2] = v.z; tile[r][cq * 4 + 3] = v.w;
  }
  __syncthreads();
  {
    const int nl = t >> 3, kq = t & 7;
    ushort h[4], l[4];
#pragma unroll
    for (int i = 0; i < 4; ++i) split2(tile[kq * 4 + i][nl], h[i], l[i]);
    ushort4 vh = {h[0], h[1], h[2], h[3]};
    ushort4 vl = {l[0], l[1], l[2], l[3]};
    *(ushort4*)(WTH + (size_t)(n0 + nl) * K + k0 + kq * 4) = vh;
    *(ushort4*)(WTL + (size_t)(n0 + nl) * K + k0 + kq * 4) = vl;
  }
}

// ---------------- K6: layer epilogue ----------------
__global__ __launch_bounds__(256) void k_postlayer(const float* __restrict__ C, const float* __restrict__ adj,
                                                   const float* __restrict__ bias,
                                                   ushort* __restrict__ HH, ushort* __restrict__ HL, int F) {
  __shared__ float adjL[64 * 65];
  __shared__ float QL[64 * 66];
  const int f0 = blockIdx.x * 64;
  const int b = blockIdx.y;
  const int t = threadIdx.x;
  const int fc = t & 63, rg = t >> 6;
  const int twoF = 2 * F;
  for (int i = t; i < 4096; i += 256) {
    const int r = i >> 6, j = i & 63;
    adjL[r * 65 + j] = adj[(size_t)b * 4096 + i];
    QL[r * 66 + j] = C[(size_t)(b * 64 + r) * twoF + F + f0 + j];
  }
  __syncthreads();
  const float bv = bias[f0 + fc];
  for (int rr = 0; rr < 16; ++rr) {
    const int r = rg * 16 + rr;
    float s = 0.f;
#pragma unroll 8
    for (int j0 = 0; j0 < 64; ++j0) {
      const int j = (j0 + fc) & 63;
      s += adjL[r * 65 + j] * QL[j * 66 + fc];
    }
    const int row = b * 64 + r;
    float h = C[(size_t)row * twoF + f0 + fc] + s + bv;
    h = fmaxf(h, 0.f);
    ushort hh, hl;
    split2(h, hh, hl);
    HH[(size_t)row * F + f0 + fc] = hh;
    HL[(size_t)row * F + f0 + fc] = hl;
  }
}

// ---------------- K7: classifier epilogue ----------------
__global__ __launch_bounds__(256) void k_postcls(const float* __restrict__ C, const float* __restrict__ bias,
                                                 const float* __restrict__ pre, float* __restrict__ HC) {
  const size_t i0 = ((size_t)blockIdx.x * 256 + threadIdx.x) * 4;
  const int col = (int)(i0 & 255);
  float4 c = *(const float4*)(C + i0);
  float o[4] = {c.x, c.y, c.z, c.w};
#pragma unroll
  for (int i = 0; i < 4; ++i) {
    float h = o[i] + bias[col + i];
    o[i] = (h > 0.f) ? h : pre[col + i] * h;
  }
  *(float4*)(HC + i0) = make_float4(o[0], o[1], o[2], o[3]);
}

// ---------------- K8: pred = HC @ Wc2 + bc2 ----------------
__global__ __launch_bounds__(256) void k_final(const float* __restrict__ Hc, const float* __restrict__ Wc2,
                                               const float* __restrict__ bc2, float* __restrict__ outp) {
  __shared__ float w[512];
  __shared__ float red[512];
  const int t = threadIdx.x;
  for (int i = t; i < 512; i += 256) w[i] = Wc2[i];
  __syncthreads();
  const int m = blockIdx.x * 64 + (t >> 2);
  const int p = t & 3;
  const float* h = Hc + (size_t)m * 256;
  float s0 = 0.f, s1 = 0.f;
  for (int k = p * 64; k < p * 64 + 64; ++k) {
    float hv = h[k];
    s0 += hv * w[k * 2];
    s1 += hv * w[k * 2 + 1];
  }
  red[t * 2] = s0; red[t * 2 + 1] = s1;
  __syncthreads();
  if (p == 0) {
    for (int q = 1; q < 4; ++q) { s0 += red[(t + q) * 2]; s1 += red[(t + q) * 2 + 1]; }
    outp[m * 2 + 0] = s0 + bc2[0];
    outp[m * 2 + 1] = s1 + bc2[1];
  }
}

extern "C" void kernel_launch(void* const* d_in, const int* in_sizes, int n_in,
                              void* d_out, int out_size, void* d_ws, size_t ws_size,
                              hipStream_t stream) {
  const int*   indexes = (const int*)d_in[0];
  const float* F   = (const float*)d_in[1];
  const float* W1  = (const float*)d_in[4];
  const float* b1  = (const float*)d_in[5];
  const float* W2  = (const float*)d_in[6];
  const float* b2  = (const float*)d_in[7];
  const float* W3  = (const float*)d_in[8];
  const float* b3  = (const float*)d_in[9];
  const float* W4  = (const float*)d_in[10];
  const float* b4  = (const float*)d_in[11];
  const float* Wc1 = (const float*)d_in[12];
  const float* bc1 = (const float*)d_in[13];
  const float* pre = (const float*)d_in[14];
  const float* Wc2 = (const float*)d_in[15];
  const float* bc2 = (const float*)d_in[16];
  float* out = (float*)d_out;

  size_t off = 0;
  auto take = [&](size_t bytes) -> char* {
    char* q = (char*)d_ws + off;
    off += (bytes + 255) & ~(size_t)255;
    return q;
  };
  float* TOPV = (float*)take((size_t)NROWS * KSEL * 4);
  int*   TOPI = (int*)  take((size_t)NROWS * KSEL * 4);
  float* EXPS = (float*)take((size_t)NROWS * 4);
  float* ADJ  = (float*)take((size_t)64 * 64 * 64 * 4);
  char*  big  = (char*)d_ws + off;
  const size_t big_bytes = (ws_size > off) ? (ws_size - off) : 0;

  const size_t Mi = 1024 * 1024;
  const size_t Ki = 1024;
  const size_t splitBytes = (size_t)NROWS * DFEAT * 2;

  if (big_bytes >= 160 * Mi) {
    ushort* FH = (ushort*)big;
    ushort* FM = (ushort*)(big + splitBytes);
    ushort* FL = (ushort*)(big + 2 * splitBytes);
    float* TILE0  = (float*)(big + 96 * Mi);
    float* TILE0T = (float*)(big + 112 * Mi);
    float* TILE1  = (float*)(big + 128 * Mi);
    float* TILE1T = (float*)(big + 144 * Mi);
    k_split<<<NROWS * DFEAT / 1024, 256, 0, stream>>>(F, FH, FM, FL);
    k_init_topk<<<NROWS * KSEL / 256, 256, 0, stream>>>(TOPV, TOPI);
    const int pairs[10][2] = {{0,0},{0,1},{0,2},{0,3},{1,1},{1,2},{1,3},{2,2},{2,3},{3,3}};
    for (int b = 0; b < 5; ++b) {
      const int ia = pairs[2*b][0],   ja = pairs[2*b][1];
      const int ib = pairs[2*b+1][0], jb = pairs[2*b+1][1];
      const int da = (ia == ja), db = (ib == jb);
      k_simgemm_pair<<<dim3(16, 16, 2), 256, 0, stream>>>(
          FH, FM, FL,
          TILE0, da ? TILE0 : TILE0T, ia, ja, da,
          TILE1, db ? TILE1 : TILE1T, ib, jb, db);
      k_topk_update<<<CHK, 256, 0, stream>>>(TILE0, ia * CHK, ja * CHK, TOPV, TOPI);
      if (!da) k_topk_update<<<CHK, 256, 0, stream>>>(TILE0T, ja * CHK, ia * CHK, TOPV, TOPI);
      k_topk_update<<<CHK, 256, 0, stream>>>(TILE1, ib * CHK, jb * CHK, TOPV, TOPI);
      if (!db) k_topk_update<<<CHK, 256, 0, stream>>>(TILE1T, jb * CHK, ib * CHK, TOPV, TOPI);
    }
    k_exps<<<NROWS / 256, 256, 0, stream>>>(TOPV, EXPS);
  } else {
    int fchunk = 0;
    for (int c = 2048; c >= 512; c >>= 1) {
      if (3 * splitBytes + (size_t)c * NROWS * 4 <= big_bytes) { fchunk = c; break; }
    }
    if (fchunk == 0) {
      hipMemsetAsync(d_out, 0, (size_t)out_size * 4, stream);
      return;
    }
    ushort* FH = (ushort*)big;
    ushort* FM = (ushort*)(big + splitBytes);
    ushort* FL = (ushort*)(big + 2 * splitBytes);
    float* SIMC = (float*)(big + 3 * splitBytes);
    k_split<<<NROWS * DFEAT / 1024, 256, 0, stream>>>(F, FH, FM, FL);
    for (int r0 = 0; r0 < NROWS; r0 += fchunk) {
      k_simgemm_mfma<<<dim3(64, fchunk / 128), 256, 0, stream>>>(FH, FM, FL, SIMC, r0);
      k_topk<<<fchunk, 256, 0, stream>>>(SIMC, TOPV, TOPI, EXPS, r0);
    }
  }
  k_adj<<<64, 256, 0, stream>>>(indexes, TOPV, TOPI, EXPS, ADJ);

  ushort* XH   = (ushort*)(big);
  ushort* XL   = (ushort*)(big + 16 * Mi);
  ushort* WT1H = (ushort*)(big + 32 * Mi);
  ushort* WT1L = (ushort*)(big + 40 * Mi);
  ushort* WT2H = (ushort*)(big + 48 * Mi);
  ushort* WT2L = (ushort*)(big + 50 * Mi);
  ushort* WT3H = (ushort*)(big + 52 * Mi);
  ushort* WT3L = (ushort*)(big + 52 * Mi + 512 * Ki);
  ushort* WT4H = (ushort*)(big + 53 * Mi);
  ushort* WT4L = (ushort*)(big + 53 * Mi + 256 * Ki);
  ushort* WTcH = (ushort*)(big + 53 * Mi + 512 * Ki);
  ushort* WTcL = (ushort*)(big + 53 * Mi + 640 * Ki);
  float*  CBUF = (float*)(big + 54 * Mi);
  float*  HC   = (float*)(big + 86 * Mi);
  ushort* H1H  = (ushort*)(big + 32 * Mi);
  ushort* H1L  = (ushort*)(big + 40 * Mi);
  ushort* H2H  = (ushort*)(big);
  ushort* H2L  = (ushort*)(big + 4 * Mi);
  ushort* H3H  = (ushort*)(big + 8 * Mi);
  ushort* H3L  = (ushort*)(big + 10 * Mi);
  ushort* H4H  = (ushort*)(big + 12 * Mi);
  ushort* H4L  = (ushort*)(big + 14 * Mi);

  k_wsplitT<<<dim3(2048 / 32, 2048 / 32), 256, 0, stream>>>(W1, WT1H, WT1L, 2048, 1024);
  k_wsplitT<<<dim3(1024 / 32, 1024 / 32), 256, 0, stream>>>(W2, WT2H, WT2L, 1024, 512);
  k_wsplitT<<<dim3(512 / 32, 512 / 32), 256, 0, stream>>>(W3, WT3H, WT3L, 512, 256);
  k_wsplitT<<<dim3(256 / 32, 512 / 32), 256, 0, stream>>>(W4, WT4H, WT4L, 256, 256);
  k_wsplitT<<<dim3(256 / 32, 256 / 32), 256, 0, stream>>>(Wc1, WTcH, WTcL, 256, 256);

  k_xs_split<<<dim3(64, 64), 256, 0, stream>>>(indexes, TOPI, F, XH, XL);

  k_gemm3<<<dim3(16, 32), 256, 0, stream>>>(XH, XL, WT1H, WT1L, CBUF, 2048, 2048);
  k_postlayer<<<dim3(16, 64), 256, 0, stream>>>(CBUF, ADJ, b1, H1H, H1L, 1024);
  k_gemm3<<<dim3(8, 32), 256, 0, stream>>>(H1H, H1L, WT2H, WT2L, CBUF, 1024, 1024);
  k_postlayer<<<dim3(8, 64), 256, 0, stream>>>(CBUF, ADJ, b2, H2H, H2L, 512);
  k_gemm3<<<dim3(4, 32), 256, 0, stream>>>(H2H, H2L, WT3H, WT3L, CBUF, 512, 512);
  k_postlayer<<<dim3(4, 64), 256, 0, stream>>>(CBUF, ADJ, b3, H3H, H3L, 256);
  k_gemm3<<<dim3(4, 32), 256, 0, stream>>>(H3H, H3L, WT4H, WT4L, CBUF, 256, 512);
  k_postlayer<<<dim3(4, 64), 256, 0, stream>>>(CBUF, ADJ, b4, H4H, H4L, 256);
  k_gemm3<<<dim3(2, 32), 256, 0, stream>>>(H4H, H4L, WTcH, WTcL, CBUF, 256, 256);
  k_postcls<<<4096 * 256 / 1024, 256, 0, stream>>>(CBUF, bc1, pre, HC);

  k_final<<<64, 256, 0, stream>>>(HC, Wc2, bc2, out);
}